// Round 5
// baseline (1870.349 us; speedup 1.0000x reference)
//
#include <hip/hip_runtime.h>

// Problem constants
#define B_   64
#define S_   2048
#define E_   1024
#define H_   512
#define EMB_ 256
#define V_   50257
#define M_   (B_*S_)

typedef __attribute__((ext_vector_type(8))) short bf16x8;   // 8 bf16 = 4 VGPR
typedef __attribute__((ext_vector_type(4))) float f32x4;

__device__ __forceinline__ unsigned short f2bf(float f) {
  unsigned int u = __float_as_uint(f);
  u += 0x7fffu + ((u >> 16) & 1u);          // round-to-nearest-even
  return (unsigned short)(u >> 16);
}
__device__ __forceinline__ unsigned pk2(float a, float b) {
  return (unsigned)f2bf(a) | ((unsigned)f2bf(b) << 16);
}
__device__ __forceinline__ float bf2f(unsigned short u) {
  return __uint_as_float(((unsigned)u) << 16);
}
__device__ __forceinline__ float sigm(float x)  { return 1.f / (1.f + __expf(-x)); }
__device__ __forceinline__ float tanh_f(float x){ return 1.f - 2.f / (1.f + __expf(2.f * x)); }

// ---------------------------------------------------------------------------
// K1a: attn_wh_w (512x1024 f32) -> bf16, PRE-SWIZZLED Bs image per K-tile:
// Wb byte [kt*65536 + n*128 + (kb ^ ((n&7)<<4))] = bf16 of whw[n][kt*64 + kb/2]
__global__ __launch_bounds__(256) void k_convw(const float* __restrict__ w,
                                               unsigned short* __restrict__ wb) {
  int i = blockIdx.x * 256 + threadIdx.x;     // 524288 ushorts
  int kt = i >> 15;
  int rem = (i << 1) & 65535;                 // byte offset within kt image
  int n = rem >> 7;
  int sb = rem & 127;
  int kb = sb ^ ((n & 7) << 4);
  int k = kt * 64 + (kb >> 1);
  wb[i] = f2bf(w[((size_t)n << 10) + k]);
}

// K1b: wsb_tot[b][n] = attn_wh_b[n] + attn_ws_b[n] + h0[b]·attn_ws_w[n]
__global__ __launch_bounds__(256) void k_wsapp(const float* __restrict__ h0,
                                               const float* __restrict__ wsw,
                                               const float* __restrict__ wsb,
                                               const float* __restrict__ whb,
                                               float* __restrict__ outw) {
  int g = blockIdx.x * 256 + threadIdx.x;
  int b = g >> 9, n = g & 511;
  const float* hr = h0 + b * 512;
  const float* wr = wsw + (size_t)n * 512;
  float acc = 0.f;
  for (int k = 0; k < 512; k += 4) {
    float4 a = *(const float4*)(hr + k);
    float4 w = *(const float4*)(wr + k);
    acc += a.x*w.x + a.y*w.y + a.z*w.z + a.w*w.w;
  }
  outw[g] = acc + wsb[n] + whb[n];
}

// ---------------------------------------------------------------------------
// K2 v4: fused energy GEMM. 256 thr / 4 waves (2m x 2n), tile 128m x 512n,
// K-step 64, As 16KB + Bs 64KB = 80KB exactly -> 2 blocks/CU.
// Both LDS tiles use the round-1-proven pattern: 128B rows, XOR (row&7)<<4,
// writes cover whole rows contiguously, reads span 16 rows. B arrives
// pre-swizzled from k_convw -> staging is a linear copy.
// Optionally also emits enc as bf16 (row-major [m][1024]) for k_ctx.
template<bool WBF>
__global__ __launch_bounds__(256, 2) void k_energy(
    const float* __restrict__ enc, const unsigned short* __restrict__ Wb,
    const float* __restrict__ wsb, const float* __restrict__ av,
    float* __restrict__ eout, unsigned short* __restrict__ encbf)
{
  __shared__ __attribute__((aligned(16))) char lds[81920];  // As [0,16384) | Bs [16384,81920)

  const int tid = threadIdx.x;
  const int w = tid >> 6, lane = tid & 63, lr = lane & 15, lg = lane >> 4;
  const int wm = w >> 1, wn = w & 1;          // wave tile 64m x 256n
  const int m0 = blockIdx.x * 128;
  const int bb = m0 >> 11;                    // batch index

  f32x4 acc[4][16];
  #pragma unroll
  for (int i = 0; i < 4; ++i)
    #pragma unroll
    for (int j = 0; j < 16; ++j)
      #pragma unroll
      for (int r = 0; r < 4; ++r) acc[i][j][r] = 0.f;

  // A staging: thread t -> row t>>1, half t&1 (32 floats -> 64B bf16)
  const int arow = tid >> 1, ah = tid & 1;
  const float* aptr = enc + ((size_t)(m0 + arow) << 10) + ah * 32;
  const int aswz = (arow & 7) << 4;
  // B staging: thread t copies 256B linearly
  const uint4* bptr = (const uint4*)((const char*)Wb + tid * 256);

  float4 ar[8]; uint4 br[16];
  auto issue = [&](int kt) {
    const float* ap = aptr + kt * 64;
    #pragma unroll
    for (int i = 0; i < 8; ++i) ar[i] = *(const float4*)(ap + i * 4);
    const uint4* bp = bptr + kt * 4096;
    #pragma unroll
    for (int i = 0; i < 16; ++i) br[i] = bp[i];
  };
  auto stage = [&](int kt) {
    uint4* bd = (uint4*)(lds + 16384 + tid * 256);
    #pragma unroll
    for (int i = 0; i < 16; ++i) bd[i] = br[i];
    uint4 pv[4];
    #pragma unroll
    for (int j = 0; j < 4; ++j) {
      pv[j].x = pk2(ar[2*j].x,   ar[2*j].y);
      pv[j].y = pk2(ar[2*j].z,   ar[2*j].w);
      pv[j].z = pk2(ar[2*j+1].x, ar[2*j+1].y);
      pv[j].w = pk2(ar[2*j+1].z, ar[2*j+1].w);
    }
    char* ab = lds + arow * 128;
    #pragma unroll
    for (int j = 0; j < 4; ++j)
      *(uint4*)(ab + ((ah * 64 + j * 16) ^ aswz)) = pv[j];
    if (WBF) {
      uint4* gd = (uint4*)((char*)encbf + ((size_t)(m0 + arow) << 11) + kt * 128 + ah * 64);
      #pragma unroll
      for (int j = 0; j < 4; ++j) gd[j] = pv[j];
    }
  };

  const int swz = (lr & 7) << 4;
  int abase[4];
  #pragma unroll
  for (int fm = 0; fm < 4; ++fm) abase[fm] = (wm * 64 + fm * 16 + lr) * 128;
  int bbase[16];
  #pragma unroll
  for (int fn = 0; fn < 16; ++fn) bbase[fn] = 16384 + (wn * 256 + fn * 16 + lr) * 128;

  issue(0);
  for (int kt = 0; kt < 16; ++kt) {
    __syncthreads();                    // previous tile's reads complete
    stage(kt);
    __syncthreads();                    // stage visible
    if (kt < 15) issue(kt + 1);         // next loads fly under compute
    #pragma unroll
    for (int ks = 0; ks < 2; ++ks) {
      const int ko = (ks * 64 + lg * 16) ^ swz;
      bf16x8 af[4];
      #pragma unroll
      for (int fm = 0; fm < 4; ++fm) af[fm] = *(const bf16x8*)(lds + abase[fm] + ko);
      #pragma unroll
      for (int fn = 0; fn < 16; ++fn) {
        bf16x8 bf = *(const bf16x8*)(lds + bbase[fn] + ko);
        #pragma unroll
        for (int fm = 0; fm < 4; ++fm)
          acc[fm][fn] = __builtin_amdgcn_mfma_f32_16x16x32_bf16(af[fm], bf, acc[fm][fn], 0, 0, 0);
      }
    }
  }

  // epilogue: e_row = sum_n av[n]*tanh(acc + wsb[b][n]); deterministic reduce
  float cw_[16], cv_[16];
  #pragma unroll
  for (int fn = 0; fn < 16; ++fn) {
    int col = wn * 256 + fn * 16 + lr;
    cw_[fn] = wsb[bb * 512 + col];
    cv_[fn] = av[col];
  }
  __syncthreads();                      // all LDS reads done; reuse As as red
  float* red = (float*)lds;             // [2 wn][128]
  #pragma unroll
  for (int fm = 0; fm < 4; ++fm) {
    #pragma unroll
    for (int r = 0; r < 4; ++r) {
      float v = 0.f;
      #pragma unroll
      for (int fn = 0; fn < 16; ++fn)
        v += cv_[fn] * tanh_f(acc[fm][fn][r] + cw_[fn]);  // C/D: col=lane&15, row=(lane>>4)*4+r
      v += __shfl_xor(v, 1); v += __shfl_xor(v, 2);
      v += __shfl_xor(v, 4); v += __shfl_xor(v, 8);
      if (lr == 0) red[wn * 128 + wm * 64 + fm * 16 + lg * 4 + r] = v;
    }
  }
  __syncthreads();
  if (tid < 128)
    eout[m0 + tid] = red[tid] + red[128 + tid];
}

// ---------------------------------------------------------------------------
// K3: softmax over S per batch
__global__ __launch_bounds__(256) void k_attnsm(const float* __restrict__ e,
                                                float* __restrict__ attn) {
  int b = blockIdx.x, tid = threadIdx.x;
  __shared__ float sm[256];
  float ev[8]; float mx = -3.0e38f;
  #pragma unroll
  for (int i = 0; i < 8; ++i) {
    float v = e[b * 2048 + i * 256 + tid];
    ev[i] = v; mx = fmaxf(mx, v);
  }
  sm[tid] = mx; __syncthreads();
  for (int st = 128; st; st >>= 1) { if (tid < st) sm[tid] = fmaxf(sm[tid], sm[tid + st]); __syncthreads(); }
  mx = sm[0]; __syncthreads();
  float sum = 0.f;
  #pragma unroll
  for (int i = 0; i < 8; ++i) { ev[i] = __expf(ev[i] - mx); sum += ev[i]; }
  sm[tid] = sum; __syncthreads();
  for (int st = 128; st; st >>= 1) { if (tid < st) sm[tid] += sm[tid + st]; __syncthreads(); }
  float inv = 1.f / sm[0];
  #pragma unroll
  for (int i = 0; i < 8; ++i) attn[b * 2048 + i * 256 + tid] = ev[i] * inv;
}

// K4a: context partials from bf16 enc (fused-path)
__global__ __launch_bounds__(256) void k_ctx_bf(const unsigned short* __restrict__ encb,
                                                const float* __restrict__ attn,
                                                float* __restrict__ cp) {
  int sc = blockIdx.x, b = blockIdx.y, tid = threadIdx.x;
  int e0 = tid * 4;
  float ax = 0.f, ay = 0.f, az = 0.f, aw = 0.f;
  const unsigned short* base = encb + (((size_t)b * 2048 + sc * 64) << 10) + e0;
  const float* awt = attn + b * 2048 + sc * 64;
  #pragma unroll 8
  for (int s = 0; s < 64; ++s) {
    float wv = awt[s];
    ushort4 v = *(const ushort4*)(base + ((size_t)s << 10));
    ax += wv * bf2f(v.x); ay += wv * bf2f(v.y);
    az += wv * bf2f(v.z); aw += wv * bf2f(v.w);
  }
  float4 o; o.x = ax; o.y = ay; o.z = az; o.w = aw;
  *(float4*)(cp + ((size_t)sc * 64 + b) * 1024 + e0) = o;
}

// K4b: fp32 fallback
__global__ __launch_bounds__(256) void k_ctx(const float* __restrict__ enc,
                                             const float* __restrict__ attn,
                                             float* __restrict__ cp) {
  int sc = blockIdx.x, b = blockIdx.y, tid = threadIdx.x;
  int e0 = tid * 4;
  float ax = 0.f, ay = 0.f, az = 0.f, aw = 0.f;
  const float* base = enc + (((size_t)b * 2048 + sc * 64) << 10) + e0;
  const float* awt = attn + b * 2048 + sc * 64;
  #pragma unroll 8
  for (int s = 0; s < 64; ++s) {
    float wv = awt[s];
    float4 v = *(const float4*)(base + ((size_t)s << 10));
    ax += wv * v.x; ay += wv * v.y; az += wv * v.z; aw += wv * v.w;
  }
  float4 o; o.x = ax; o.y = ay; o.z = az; o.w = aw;
  *(float4*)(cp + ((size_t)sc * 64 + b) * 1024 + e0) = o;
}

// K5a: reduce context, build xb[b][k], cw[b] = ctx·wh_vec + embed·wx_vec
__global__ __launch_bounds__(256) void k_xprep(const float* __restrict__ cp,
                                               const float* __restrict__ et,
                                               const int* __restrict__ dec,
                                               const float* __restrict__ h0,
                                               const float* __restrict__ whv,
                                               const float* __restrict__ wxv,
                                               float* __restrict__ xb,
                                               float* __restrict__ cw) {
  int b = blockIdx.x, tid = threadIdx.x;
  __shared__ float sm[256];
  float acc = 0.f;
  for (int j = tid; j < 1024; j += 256) {
    float s = 0.f;
    #pragma unroll
    for (int sc = 0; sc < 32; ++sc) s += cp[((size_t)sc * 64 + b) * 1024 + j];
    xb[b * 1792 + j] = s;
    acc += s * whv[j];
  }
  int e = dec[b];
  {
    int j = tid;
    float s = et[(size_t)e * 256 + j];
    xb[b * 1792 + 1024 + j] = s;
    acc += s * wxv[j];
  }
  for (int j = tid; j < 512; j += 256)
    xb[b * 1792 + 1280 + j] = h0[b * 512 + j];
  sm[tid] = acc; __syncthreads();
  for (int st = 128; st; st >>= 1) { if (tid < st) sm[tid] += sm[tid + st]; __syncthreads(); }
  if (!tid) cw[b] = sm[0];
}

// K5b: gate partials via MFMA. Block = 64 j-rows x 64 b, k-slab 448.
__global__ __launch_bounds__(256, 2) void k_gates(const float* __restrict__ wih,
                                                  const float* __restrict__ whh,
                                                  const float* __restrict__ xb,
                                                  float* __restrict__ gp) {
  __shared__ __attribute__((aligned(16))) char Bs[56 * 1040];
  const int tid = threadIdx.x;
  const int w = tid >> 6, lane = tid & 63, lr = lane & 15, lg = lane >> 4;
  const int j0 = blockIdx.x * 64;
  const int sl = blockIdx.y;
  const int k0 = sl * 448;

  #pragma unroll
  for (int i = 0; i < 16; ++i) {
    int slot = i * 256 + tid;
    int kq = slot & 63, n = slot >> 6;
    if (kq < 56) {
      const float4* p = (const float4*)(xb + n * 1792 + k0 + kq * 8);
      float4 x0 = p[0], x1 = p[1];
      uint4 pv;
      pv.x = pk2(x0.x, x0.y); pv.y = pk2(x0.z, x0.w);
      pv.z = pk2(x1.x, x1.y); pv.w = pk2(x1.z, x1.w);
      *(uint4*)(Bs + kq * 1040 + n * 16) = pv;
    }
  }
  __syncthreads();

  f32x4 acc[4];
  #pragma unroll
  for (int fn = 0; fn < 4; ++fn)
    #pragma unroll
    for (int r = 0; r < 4; ++r) acc[fn][r] = 0.f;

  const int j = j0 + w * 16 + lr;
  for (int ks = 0; ks < 14; ++ks) {
    int kg = k0 + ks * 32 + lg * 8;
    const float* ap = (kg < 1280) ? (wih + (size_t)j * 1280 + kg)
                                  : (whh + (size_t)j * 512 + (kg - 1280));
    float4 x0 = *(const float4*)ap, x1 = *(const float4*)(ap + 4);
    bf16x8 af;
    unsigned* au = (unsigned*)&af;
    au[0] = pk2(x0.x, x0.y); au[1] = pk2(x0.z, x0.w);
    au[2] = pk2(x1.x, x1.y); au[3] = pk2(x1.z, x1.w);
    #pragma unroll
    for (int fn = 0; fn < 4; ++fn) {
      bf16x8 bf = *(const bf16x8*)(Bs + (ks * 4 + lg) * 1040 + (fn * 16 + lr) * 16);
      acc[fn] = __builtin_amdgcn_mfma_f32_16x16x32_bf16(af, bf, acc[fn], 0, 0, 0);
    }
  }
  #pragma unroll
  for (int fn = 0; fn < 4; ++fn) {
    int b = fn * 16 + lr;
    #pragma unroll
    for (int r = 0; r < 4; ++r) {
      int jr = j0 + w * 16 + lg * 4 + r;
      gp[((size_t)sl * 64 + b) * 2048 + jr] = acc[fn][r];
    }
  }
}

// K5c: LSTM cell + h_t,c_t outputs + p_gen (reduce 4 k-slabs)
__global__ __launch_bounds__(512) void k_lstm(const float* __restrict__ gp,
                                              const float* __restrict__ bih,
                                              const float* __restrict__ bhh,
                                              const float* __restrict__ c0,
                                              const float* __restrict__ cw,
                                              const float* __restrict__ wsv,
                                              float* __restrict__ dout,
                                              float* __restrict__ pg) {
  int b = blockIdx.x, h = threadIdx.x;
  __shared__ float sm[512];
  float gi = bih[h]        + bhh[h];
  float gf = bih[512 + h]  + bhh[512 + h];
  float gg = bih[1024 + h] + bhh[1024 + h];
  float go = bih[1536 + h] + bhh[1536 + h];
  #pragma unroll
  for (int kc = 0; kc < 4; ++kc) {
    const float* g = gp + ((size_t)kc * 64 + b) * 2048;
    gi += g[h]; gf += g[512 + h]; gg += g[1024 + h]; go += g[1536 + h];
  }
  float c  = sigm(gf) * c0[b * 512 + h] + sigm(gi) * tanh_f(gg);
  float ht = sigm(go) * tanh_f(c);
  dout[(size_t)B_ * V_ + b * 512 + h] = ht;
  dout[(size_t)B_ * V_ + B_ * H_ + b * 512 + h] = c;
  sm[h] = ht * wsv[h];
  __syncthreads();
  for (int st = 256; st; st >>= 1) { if (h < st) sm[h] += sm[h + st]; __syncthreads(); }
  if (!h) pg[b] = sigm(cw[b] + sm[0]);
}

// K6: vocab logits via MFMA. Block = 128 v-rows x all 64 batches.
__global__ __launch_bounds__(256, 2) void k_logits(const float* __restrict__ vw,
                                                   const float* __restrict__ vb,
                                                   const float* __restrict__ ht,
                                                   float* __restrict__ out) {
  __shared__ __attribute__((aligned(16))) char Bs[64 * 1040];
  const int tid = threadIdx.x;
  const int w = tid >> 6, lane = tid & 63, lr = lane & 15, lg = lane >> 4;
  const int v0 = blockIdx.x * 128;

  #pragma unroll
  for (int i = 0; i < 16; ++i) {
    int slot = i * 256 + tid;
    int kq = slot & 63, n = slot >> 6;
    const float4* p = (const float4*)(ht + n * 512 + kq * 8);
    float4 x0 = p[0], x1 = p[1];
    uint4 pv;
    pv.x = pk2(x0.x, x0.y); pv.y = pk2(x0.z, x0.w);
    pv.z = pk2(x1.x, x1.y); pv.w = pk2(x1.z, x1.w);
    *(uint4*)(Bs + kq * 1040 + n * 16) = pv;
  }
  __syncthreads();

  f32x4 acc[2][4];
  #pragma unroll
  for (int fm = 0; fm < 2; ++fm)
    #pragma unroll
    for (int fn = 0; fn < 4; ++fn)
      #pragma unroll
      for (int r = 0; r < 4; ++r) acc[fm][fn][r] = 0.f;

  int row0 = v0 + w * 32 + lr;
  int row1 = row0 + 16;
  const float* a0p = vw + (size_t)min(row0, V_ - 1) * 512 + lg * 8;
  const float* a1p = vw + (size_t)min(row1, V_ - 1) * 512 + lg * 8;

  float4 pa0[2], pa1[2];
  pa0[0] = *(const float4*)a0p; pa0[1] = *(const float4*)(a0p + 4);
  pa1[0] = *(const float4*)a1p; pa1[1] = *(const float4*)(a1p + 4);

  for (int ks = 0; ks < 16; ++ks) {
    bf16x8 af0, af1;
    {
      unsigned* u = (unsigned*)&af0;
      u[0] = pk2(pa0[0].x, pa0[0].y); u[1] = pk2(pa0[0].z, pa0[0].w);
      u[2] = pk2(pa0[1].x, pa0[1].y); u[3] = pk2(pa0[1].z, pa0[1].w);
      unsigned* v = (unsigned*)&af1;
      v[0] = pk2(pa1[0].x, pa1[0].y); v[1] = pk2(pa1[0].z, pa1[0].w);
      v[2] = pk2(pa1[1].x, pa1[1].y); v[3] = pk2(pa1[1].z, pa1[1].w);
    }
    if (ks < 15) {
      const float* n0 = a0p + (ks + 1) * 32;
      const float* n1 = a1p + (ks + 1) * 32;
      pa0[0] = *(const float4*)n0; pa0[1] = *(const float4*)(n0 + 4);
      pa1[0] = *(const float4*)n1; pa1[1] = *(const float4*)(n1 + 4);
    }
    const char* bbase = Bs + (ks * 4 + lg) * 1040 + lr * 16;
    #pragma unroll
    for (int fn = 0; fn < 4; ++fn) {
      bf16x8 bf = *(const bf16x8*)(bbase + fn * 256);
      acc[0][fn] = __builtin_amdgcn_mfma_f32_16x16x32_bf16(af0, bf, acc[0][fn], 0, 0, 0);
      acc[1][fn] = __builtin_amdgcn_mfma_f32_16x16x32_bf16(af1, bf, acc[1][fn], 0, 0, 0);
    }
  }

  #pragma unroll
  for (int fm = 0; fm < 2; ++fm) {
    #pragma unroll
    for (int r = 0; r < 4; ++r) {
      int vrow = v0 + w * 32 + fm * 16 + lg * 4 + r;
      if (vrow < V_) {
        float bias = vb[vrow];
        #pragma unroll
        for (int fn = 0; fn < 4; ++fn) {
          int b = fn * 16 + lr;
          out[(size_t)b * V_ + vrow] = acc[fm][fn][r] + bias;
        }
      }
    }
  }
}

// K7a: per-(chunk,batch) softmax partials over V
#define VCH 6283
__global__ __launch_bounds__(256) void k_sm1(const float* __restrict__ out,
                                             float* __restrict__ pst) {
  int c = blockIdx.x, b = blockIdx.y, tid = threadIdx.x;
  __shared__ float sm[256];
  const float* row = out + (size_t)b * V_;
  int v0 = c * VCH, v1 = min(v0 + VCH, V_);
  float mx = -3.0e38f;
  for (int v = v0 + tid; v < v1; v += 256) mx = fmaxf(mx, row[v]);
  sm[tid] = mx; __syncthreads();
  for (int st = 128; st; st >>= 1) { if (tid < st) sm[tid] = fmaxf(sm[tid], sm[tid + st]); __syncthreads(); }
  mx = sm[0]; __syncthreads();
  float sum = 0.f;
  for (int v = v0 + tid; v < v1; v += 256) sum += __expf(row[v] - mx);
  sm[tid] = sum; __syncthreads();
  for (int st = 128; st; st >>= 1) { if (tid < st) sm[tid] += sm[tid + st]; __syncthreads(); }
  if (!tid) { pst[(b * 8 + c) * 2] = mx; pst[(b * 8 + c) * 2 + 1] = sm[0]; }
}

// K7b: merge chunk partials
__global__ __launch_bounds__(64) void k_sm2(const float* __restrict__ pst,
                                            float* __restrict__ stats) {
  int b = threadIdx.x;
  float mx = -3.0e38f;
  #pragma unroll
  for (int c = 0; c < 8; ++c) mx = fmaxf(mx, pst[(b * 8 + c) * 2]);
  float s = 0.f;
  #pragma unroll
  for (int c = 0; c < 8; ++c)
    s += pst[(b * 8 + c) * 2 + 1] * __expf(pst[(b * 8 + c) * 2] - mx);
  stats[b * 2] = mx; stats[b * 2 + 1] = s;
}

// K8: out = p_gen * softmax(logits) in place
__global__ __launch_bounds__(256) void k_final(float* __restrict__ out,
                                               const float* __restrict__ stats,
                                               const float* __restrict__ pg) {
  int v = blockIdx.x * 256 + threadIdx.x;
  int b = blockIdx.y;
  if (v < V_) {
    float mx = stats[b * 2];
    float scale = pg[b] / stats[b * 2 + 1];
    size_t i = (size_t)b * V_ + v;
    out[i] = scale * __expf(out[i] - mx);
  }
}

// K9: scatter attention into vocab
__global__ __launch_bounds__(256) void k_scatter(float* __restrict__ out,
                                                 const float* __restrict__ attn,
                                                 const int* __restrict__ einp,
                                                 const float* __restrict__ pg) {
  int b = blockIdx.y;
  int s = blockIdx.x * 256 + threadIdx.x;
  int v = einp[b * 2048 + s];
  float w = (1.f - pg[b]) * attn[b * 2048 + s];
  atomicAdd(out + (size_t)b * V_ + v, w);
}

// ---------------------------------------------------------------------------
extern "C" void kernel_launch(void* const* d_in, const int* in_sizes, int n_in,
                              void* d_out, int out_size, void* d_ws, size_t ws_size,
                              hipStream_t stream) {
  const float* enc  = (const float*)d_in[0];
  const float* h0   = (const float*)d_in[1];
  const float* c0   = (const float*)d_in[2];
  const int*   dec  = (const int*)d_in[3];
  const int*   einp = (const int*)d_in[4];
  const float* et   = (const float*)d_in[5];
  const float* whw  = (const float*)d_in[6];
  const float* whb  = (const float*)d_in[7];
  const float* wsw  = (const float*)d_in[8];
  const float* wsbv = (const float*)d_in[9];
  const float* av   = (const float*)d_in[10];
  const float* wih  = (const float*)d_in[11];
  const float* whh  = (const float*)d_in[12];
  const float* bih  = (const float*)d_in[13];
  const float* bhh  = (const float*)d_in[14];
  const float* whv  = (const float*)d_in[15];
  const float* wsv  = (const float*)d_in[16];
  const float* wxv  = (const float*)d_in[17];
  const float* vw   = (const float*)d_in[18];
  const float* vb   = (const float*)d_in[19];
  float* out = (float*)d_out;

  char* ws = (char*)d_ws;
  unsigned short* Wb = (unsigned short*)(ws + 0);        // 1,048,576
  float* wsbt  = (float*)(ws + 1048576);                 //   131,072
  float* e     = (float*)(ws + 1179648);                 //   524,288
  float* attn  = (float*)(ws + 1703936);                 //   524,288
  float* cpgp  = (float*)(ws + 2228224);                 // 8,388,608 (cp, then gp)
  float* xb    = (float*)(ws + 10616832);                //   458,752
  float* cw    = (float*)(ws + 11075584);                //       256
  float* pg    = (float*)(ws + 11075840);                //       256
  float* stats = (float*)(ws + 11076096);                //       512
  float* pst   = (float*)(ws + 11076608);                //     4,096
  unsigned short* encbf = (unsigned short*)(ws + 16777216); // 268,435,456 (optional)

  const bool fused = ws_size >= (size_t)16777216 + (size_t)268435456;

  k_convw  <<<2048, 256, 0, stream>>>(whw, Wb);
  k_wsapp  <<<128, 256, 0, stream>>>(h0, wsw, wsbv, whb, wsbt);
  if (fused) {
    k_energy<true> <<<1024, 256, 0, stream>>>(enc, Wb, wsbt, av, e, encbf);
    k_attnsm <<<64, 256, 0, stream>>>(e, attn);
    k_ctx_bf <<<dim3(32, 64), 256, 0, stream>>>(encbf, attn, cpgp);
  } else {
    k_energy<false> <<<1024, 256, 0, stream>>>(enc, Wb, wsbt, av, e, nullptr);
    k_attnsm <<<64, 256, 0, stream>>>(e, attn);
    k_ctx    <<<dim3(32, 64), 256, 0, stream>>>(enc, attn, cpgp);
  }
  k_xprep  <<<64, 256, 0, stream>>>(cpgp, et, dec, h0, whv, wxv, xb, cw);
  k_gates  <<<dim3(32, 4), 256, 0, stream>>>(wih, whh, xb, cpgp);
  k_lstm   <<<64, 512, 0, stream>>>(cpgp, bih, bhh, c0, cw, wsv, out, pg);
  k_logits <<<393, 256, 0, stream>>>(vw, vb, out + (size_t)B_ * V_, out);
  k_sm1    <<<dim3(8, 64), 256, 0, stream>>>(out, pst);
  k_sm2    <<<1, 64, 0, stream>>>(pst, stats);
  k_final  <<<dim3(197, 64), 256, 0, stream>>>(out, stats, pg);
  k_scatter<<<dim3(8, 64), 256, 0, stream>>>(out, attn, einp, pg);
}

// Round 8
// 1787.302 us; speedup vs baseline: 1.0465x; 1.0465x over previous
//
#include <hip/hip_runtime.h>

// Problem constants
#define B_   64
#define S_   2048
#define E_   1024
#define H_   512
#define EMB_ 256
#define V_   50257
#define M_   (B_*S_)

typedef __attribute__((ext_vector_type(8))) short bf16x8;   // 8 bf16 = 4 VGPR
typedef __attribute__((ext_vector_type(4))) float f32x4;

__device__ __forceinline__ unsigned short f2bf(float f) {
  unsigned int u = __float_as_uint(f);
  u += 0x7fffu + ((u >> 16) & 1u);          // round-to-nearest-even
  return (unsigned short)(u >> 16);
}
__device__ __forceinline__ unsigned pk2(float a, float b) {
  return (unsigned)f2bf(a) | ((unsigned)f2bf(b) << 16);
}
__device__ __forceinline__ float sigm(float x)  { return 1.f / (1.f + __expf(-x)); }
__device__ __forceinline__ float tanh_f(float x){ return 1.f - 2.f / (1.f + __expf(2.f * x)); }

// ---------------------------------------------------------------------------
// K1a: attn_wh_w (512x1024 f32) -> bf16, PRE-SWIZZLED Bs image per K-tile:
// Wb byte [kt*65536 + n*128 + (kb ^ ((n&7)<<4))] = bf16 of whw[n][kt*64 + kb/2]
__global__ __launch_bounds__(256) void k_convw(const float* __restrict__ w,
                                               unsigned short* __restrict__ wb) {
  int i = blockIdx.x * 256 + threadIdx.x;     // 524288 ushorts
  int kt = i >> 15;
  int rem = (i << 1) & 65535;                 // byte offset within kt image
  int n = rem >> 7;
  int sb = rem & 127;
  int kb = sb ^ ((n & 7) << 4);
  int k = kt * 64 + (kb >> 1);
  wb[i] = f2bf(w[((size_t)n << 10) + k]);
}

// K1b: wsb_tot[b][n] = attn_wh_b[n] + attn_ws_b[n] + h0[b]·attn_ws_w[n]
__global__ __launch_bounds__(256) void k_wsapp(const float* __restrict__ h0,
                                               const float* __restrict__ wsw,
                                               const float* __restrict__ wsb,
                                               const float* __restrict__ whb,
                                               float* __restrict__ outw) {
  int g = blockIdx.x * 256 + threadIdx.x;
  int b = g >> 9, n = g & 511;
  const float* hr = h0 + b * 512;
  const float* wr = wsw + (size_t)n * 512;
  float acc = 0.f;
  for (int k = 0; k < 512; k += 4) {
    float4 a = *(const float4*)(hr + k);
    float4 w = *(const float4*)(wr + k);
    acc += a.x*w.x + a.y*w.y + a.z*w.z + a.w*w.w;
  }
  outw[g] = acc + wsb[n] + whb[n];
}

// ---------------------------------------------------------------------------
// K2 v6: fused energy GEMM. 256 thr / 4 waves (2m x 2n), tile 128m x 512n,
// K-step 64, As 16KB + Bs 64KB = 80KB -> 2 blocks/CU. enc fetched exactly once.
// All LDS traffic lane-contiguous or XOR-uniform (verified 8 lanes/bank-group).
__global__ __launch_bounds__(256, 2) void k_energy(
    const float* __restrict__ enc, const unsigned short* __restrict__ Wb,
    const float* __restrict__ wsb, const float* __restrict__ av,
    float* __restrict__ eout)
{
  __shared__ __attribute__((aligned(16))) char lds[81920];  // As [0,16384) | Bs [16384,81920)

  const int tid = threadIdx.x;
  const int w = tid >> 6, lane = tid & 63, lr = lane & 15, lg = lane >> 4;
  const int wm = w >> 1, wn = w & 1;          // wave tile 64m x 256n
  const int m0 = blockIdx.x * 128;
  const int bb = m0 >> 11;                    // batch index

  f32x4 acc[4][16];
  #pragma unroll
  for (int i = 0; i < 4; ++i)
    #pragma unroll
    for (int j = 0; j < 16; ++j)
      #pragma unroll
      for (int r = 0; r < 4; ++r) acc[i][j][r] = 0.f;

  // A staging: thread t -> row t>>1, half t&1 (32 floats -> 64B bf16)
  const int arow = tid >> 1, ah = tid & 1;
  const float* aptr = enc + ((size_t)(m0 + arow) << 10) + ah * 32;
  const int aswz = (arow & 7) << 4;

  float4 ar[8]; uint4 br[16];
  auto issue = [&](int kt) {
    const float* ap = aptr + kt * 64;
    #pragma unroll
    for (int i = 0; i < 8; ++i) ar[i] = *(const float4*)(ap + i * 4);
    // B: lane-contiguous linear read of pre-swizzled image
    const uint4* bp = (const uint4*)Wb + kt * 4096;
    #pragma unroll
    for (int i = 0; i < 16; ++i) br[i] = bp[i * 256 + tid];
  };
  auto stage = [&]() {
    // B: lane-contiguous linear LDS write (round-1-proven, 0 conflicts)
    uint4* bd = (uint4*)(lds + 16384);
    #pragma unroll
    for (int i = 0; i < 16; ++i) bd[i * 256 + tid] = br[i];
    uint4 pv[4];
    #pragma unroll
    for (int j = 0; j < 4; ++j) {
      pv[j].x = pk2(ar[2*j].x,   ar[2*j].y);
      pv[j].y = pk2(ar[2*j].z,   ar[2*j].w);
      pv[j].z = pk2(ar[2*j+1].x, ar[2*j+1].y);
      pv[j].w = pk2(ar[2*j+1].z, ar[2*j+1].w);
    }
    char* ab = lds + arow * 128;
    #pragma unroll
    for (int j = 0; j < 4; ++j)
      *(uint4*)(ab + ((ah * 64 + j * 16) ^ aswz)) = pv[j];
  };

  const int swz = (lr & 7) << 4;
  int abase[4];
  #pragma unroll
  for (int fm = 0; fm < 4; ++fm) abase[fm] = (wm * 64 + fm * 16 + lr) * 128;
  int bbase[16];
  #pragma unroll
  for (int fn = 0; fn < 16; ++fn) bbase[fn] = 16384 + (wn * 256 + fn * 16 + lr) * 128;

  issue(0);
  for (int kt = 0; kt < 16; ++kt) {
    __syncthreads();                    // previous tile's reads complete
    stage();
    __syncthreads();                    // stage visible
    if (kt < 15) issue(kt + 1);         // next loads fly under compute
    #pragma unroll
    for (int ks = 0; ks < 2; ++ks) {
      const int ko = (ks * 64 + lg * 16) ^ swz;
      bf16x8 af[4];
      #pragma unroll
      for (int fm = 0; fm < 4; ++fm) af[fm] = *(const bf16x8*)(lds + abase[fm] + ko);
      #pragma unroll
      for (int fn = 0; fn < 16; ++fn) {
        bf16x8 bf = *(const bf16x8*)(lds + bbase[fn] + ko);
        #pragma unroll
        for (int fm = 0; fm < 4; ++fm)
          acc[fm][fn] = __builtin_amdgcn_mfma_f32_16x16x32_bf16(af[fm], bf, acc[fm][fn], 0, 0, 0);
      }
    }
  }

  // epilogue: e_row = sum_n av[n]*tanh(acc + wsb[b][n]); deterministic reduce
  float cw_[16], cv_[16];
  #pragma unroll
  for (int fn = 0; fn < 16; ++fn) {
    int col = wn * 256 + fn * 16 + lr;
    cw_[fn] = wsb[bb * 512 + col];
    cv_[fn] = av[col];
  }
  __syncthreads();                      // all LDS reads done; reuse As as red
  float* red = (float*)lds;             // [2 wn][128]
  #pragma unroll
  for (int fm = 0; fm < 4; ++fm) {
    #pragma unroll
    for (int r = 0; r < 4; ++r) {
      float v = 0.f;
      #pragma unroll
      for (int fn = 0; fn < 16; ++fn)
        v += cv_[fn] * tanh_f(acc[fm][fn][r] + cw_[fn]);  // C/D: col=lane&15, row=(lane>>4)*4+r
      v += __shfl_xor(v, 1); v += __shfl_xor(v, 2);
      v += __shfl_xor(v, 4); v += __shfl_xor(v, 8);
      if (lr == 0) red[wn * 128 + wm * 64 + fm * 16 + lg * 4 + r] = v;
    }
  }
  __syncthreads();
  if (tid < 128)
    eout[m0 + tid] = red[tid] + red[128 + tid];
}

// ---------------------------------------------------------------------------
// K3: softmax over S per batch
__global__ __launch_bounds__(256) void k_attnsm(const float* __restrict__ e,
                                                float* __restrict__ attn) {
  int b = blockIdx.x, tid = threadIdx.x;
  __shared__ float sm[256];
  float ev[8]; float mx = -3.0e38f;
  #pragma unroll
  for (int i = 0; i < 8; ++i) {
    float v = e[b * 2048 + i * 256 + tid];
    ev[i] = v; mx = fmaxf(mx, v);
  }
  sm[tid] = mx; __syncthreads();
  for (int st = 128; st; st >>= 1) { if (tid < st) sm[tid] = fmaxf(sm[tid], sm[tid + st]); __syncthreads(); }
  mx = sm[0]; __syncthreads();
  float sum = 0.f;
  #pragma unroll
  for (int i = 0; i < 8; ++i) { ev[i] = __expf(ev[i] - mx); sum += ev[i]; }
  sm[tid] = sum; __syncthreads();
  for (int st = 128; st; st >>= 1) { if (tid < st) sm[tid] += sm[tid + st]; __syncthreads(); }
  float inv = 1.f / sm[0];
  #pragma unroll
  for (int i = 0; i < 8; ++i) attn[b * 2048 + i * 256 + tid] = ev[i] * inv;
}

// K4: context partials over 32 s-chunks of 64
__global__ __launch_bounds__(256) void k_ctx(const float* __restrict__ enc,
                                             const float* __restrict__ attn,
                                             float* __restrict__ cp) {
  int sc = blockIdx.x, b = blockIdx.y, tid = threadIdx.x;
  int e0 = tid * 4;
  float ax = 0.f, ay = 0.f, az = 0.f, aw = 0.f;
  const float* base = enc + (((size_t)b * 2048 + sc * 64) << 10) + e0;
  const float* awt = attn + b * 2048 + sc * 64;
  #pragma unroll 8
  for (int s = 0; s < 64; ++s) {
    float wv = awt[s];
    float4 v = *(const float4*)(base + ((size_t)s << 10));
    ax += wv * v.x; ay += wv * v.y; az += wv * v.z; aw += wv * v.w;
  }
  float4 o; o.x = ax; o.y = ay; o.z = az; o.w = aw;
  *(float4*)(cp + ((size_t)sc * 64 + b) * 1024 + e0) = o;
}

// K5a: reduce context, build xb[b][k], cw[b] = ctx·wh_vec + embed·wx_vec
__global__ __launch_bounds__(256) void k_xprep(const float* __restrict__ cp,
                                               const float* __restrict__ et,
                                               const int* __restrict__ dec,
                                               const float* __restrict__ h0,
                                               const float* __restrict__ whv,
                                               const float* __restrict__ wxv,
                                               float* __restrict__ xb,
                                               float* __restrict__ cw) {
  int b = blockIdx.x, tid = threadIdx.x;
  __shared__ float sm[256];
  float acc = 0.f;
  for (int j = tid; j < 1024; j += 256) {
    float s = 0.f;
    #pragma unroll
    for (int sc = 0; sc < 32; ++sc) s += cp[((size_t)sc * 64 + b) * 1024 + j];
    xb[b * 1792 + j] = s;
    acc += s * whv[j];
  }
  int e = dec[b];
  {
    int j = tid;
    float s = et[(size_t)e * 256 + j];
    xb[b * 1792 + 1024 + j] = s;
    acc += s * wxv[j];
  }
  for (int j = tid; j < 512; j += 256)
    xb[b * 1792 + 1280 + j] = h0[b * 512 + j];
  sm[tid] = acc; __syncthreads();
  for (int st = 128; st; st >>= 1) { if (tid < st) sm[tid] += sm[tid + st]; __syncthreads(); }
  if (!tid) cw[b] = sm[0];
}

// K5b: gate partials via MFMA. Block = 64 j-rows x 64 b, k-slab 448.
__global__ __launch_bounds__(256, 2) void k_gates(const float* __restrict__ wih,
                                                  const float* __restrict__ whh,
                                                  const float* __restrict__ xb,
                                                  float* __restrict__ gp) {
  __shared__ __attribute__((aligned(16))) char Bs[56 * 1040];
  const int tid = threadIdx.x;
  const int w = tid >> 6, lane = tid & 63, lr = lane & 15, lg = lane >> 4;
  const int j0 = blockIdx.x * 64;
  const int sl = blockIdx.y;
  const int k0 = sl * 448;

  #pragma unroll
  for (int i = 0; i < 16; ++i) {
    int slot = i * 256 + tid;
    int kq = slot & 63, n = slot >> 6;
    if (kq < 56) {
      const float4* p = (const float4*)(xb + n * 1792 + k0 + kq * 8);
      float4 x0 = p[0], x1 = p[1];
      uint4 pv;
      pv.x = pk2(x0.x, x0.y); pv.y = pk2(x0.z, x0.w);
      pv.z = pk2(x1.x, x1.y); pv.w = pk2(x1.z, x1.w);
      *(uint4*)(Bs + kq * 1040 + n * 16) = pv;
    }
  }
  __syncthreads();

  f32x4 acc[4];
  #pragma unroll
  for (int fn = 0; fn < 4; ++fn)
    #pragma unroll
    for (int r = 0; r < 4; ++r) acc[fn][r] = 0.f;

  const int j = j0 + w * 16 + lr;
  for (int ks = 0; ks < 14; ++ks) {
    int kg = k0 + ks * 32 + lg * 8;
    const float* ap = (kg < 1280) ? (wih + (size_t)j * 1280 + kg)
                                  : (whh + (size_t)j * 512 + (kg - 1280));
    float4 x0 = *(const float4*)ap, x1 = *(const float4*)(ap + 4);
    bf16x8 af;
    unsigned* au = (unsigned*)&af;
    au[0] = pk2(x0.x, x0.y); au[1] = pk2(x0.z, x0.w);
    au[2] = pk2(x1.x, x1.y); au[3] = pk2(x1.z, x1.w);
    #pragma unroll
    for (int fn = 0; fn < 4; ++fn) {
      bf16x8 bf = *(const bf16x8*)(Bs + (ks * 4 + lg) * 1040 + (fn * 16 + lr) * 16);
      acc[fn] = __builtin_amdgcn_mfma_f32_16x16x32_bf16(af, bf, acc[fn], 0, 0, 0);
    }
  }
  #pragma unroll
  for (int fn = 0; fn < 4; ++fn) {
    int b = fn * 16 + lr;
    #pragma unroll
    for (int r = 0; r < 4; ++r) {
      int jr = j0 + w * 16 + lg * 4 + r;
      gp[((size_t)sl * 64 + b) * 2048 + jr] = acc[fn][r];
    }
  }
}

// K5c: LSTM cell + h_t,c_t outputs + p_gen (reduce 4 k-slabs)
__global__ __launch_bounds__(512) void k_lstm(const float* __restrict__ gp,
                                              const float* __restrict__ bih,
                                              const float* __restrict__ bhh,
                                              const float* __restrict__ c0,
                                              const float* __restrict__ cw,
                                              const float* __restrict__ wsv,
                                              float* __restrict__ dout,
                                              float* __restrict__ pg) {
  int b = blockIdx.x, h = threadIdx.x;
  __shared__ float sm[512];
  float gi = bih[h]        + bhh[h];
  float gf = bih[512 + h]  + bhh[512 + h];
  float gg = bih[1024 + h] + bhh[1024 + h];
  float go = bih[1536 + h] + bhh[1536 + h];
  #pragma unroll
  for (int kc = 0; kc < 4; ++kc) {
    const float* g = gp + ((size_t)kc * 64 + b) * 2048;
    gi += g[h]; gf += g[512 + h]; gg += g[1024 + h]; go += g[1536 + h];
  }
  float c  = sigm(gf) * c0[b * 512 + h] + sigm(gi) * tanh_f(gg);
  float ht = sigm(go) * tanh_f(c);
  dout[(size_t)B_ * V_ + b * 512 + h] = ht;
  dout[(size_t)B_ * V_ + B_ * H_ + b * 512 + h] = c;
  sm[h] = ht * wsv[h];
  __syncthreads();
  for (int st = 256; st; st >>= 1) { if (h < st) sm[h] += sm[h + st]; __syncthreads(); }
  if (!h) pg[b] = sigm(cw[b] + sm[0]);
}

// K6: vocab logits via MFMA. Block = 128 v-rows x all 64 batches.
__global__ __launch_bounds__(256, 2) void k_logits(const float* __restrict__ vw,
                                                   const float* __restrict__ vb,
                                                   const float* __restrict__ ht,
                                                   float* __restrict__ out) {
  __shared__ __attribute__((aligned(16))) char Bs[64 * 1040];
  const int tid = threadIdx.x;
  const int w = tid >> 6, lane = tid & 63, lr = lane & 15, lg = lane >> 4;
  const int v0 = blockIdx.x * 128;

  #pragma unroll
  for (int i = 0; i < 16; ++i) {
    int slot = i * 256 + tid;
    int kq = slot & 63, n = slot >> 6;
    const float4* p = (const float4*)(ht + n * 512 + kq * 8);
    float4 x0 = p[0], x1 = p[1];
    uint4 pv;
    pv.x = pk2(x0.x, x0.y); pv.y = pk2(x0.z, x0.w);
    pv.z = pk2(x1.x, x1.y); pv.w = pk2(x1.z, x1.w);
    *(uint4*)(Bs + kq * 1040 + n * 16) = pv;
  }
  __syncthreads();

  f32x4 acc[2][4];
  #pragma unroll
  for (int fm = 0; fm < 2; ++fm)
    #pragma unroll
    for (int fn = 0; fn < 4; ++fn)
      #pragma unroll
      for (int r = 0; r < 4; ++r) acc[fm][fn][r] = 0.f;

  int row0 = v0 + w * 32 + lr;
  int row1 = row0 + 16;
  const float* a0p = vw + (size_t)min(row0, V_ - 1) * 512 + lg * 8;
  const float* a1p = vw + (size_t)min(row1, V_ - 1) * 512 + lg * 8;

  float4 pa0[2], pa1[2];
  pa0[0] = *(const float4*)a0p; pa0[1] = *(const float4*)(a0p + 4);
  pa1[0] = *(const float4*)a1p; pa1[1] = *(const float4*)(a1p + 4);

  for (int ks = 0; ks < 16; ++ks) {
    bf16x8 af0, af1;
    {
      unsigned* u = (unsigned*)&af0;
      u[0] = pk2(pa0[0].x, pa0[0].y); u[1] = pk2(pa0[0].z, pa0[0].w);
      u[2] = pk2(pa0[1].x, pa0[1].y); u[3] = pk2(pa0[1].z, pa0[1].w);
      unsigned* v = (unsigned*)&af1;
      v[0] = pk2(pa1[0].x, pa1[0].y); v[1] = pk2(pa1[0].z, pa1[0].w);
      v[2] = pk2(pa1[1].x, pa1[1].y); v[3] = pk2(pa1[1].z, pa1[1].w);
    }
    if (ks < 15) {
      const float* n0 = a0p + (ks + 1) * 32;
      const float* n1 = a1p + (ks + 1) * 32;
      pa0[0] = *(const float4*)n0; pa0[1] = *(const float4*)(n0 + 4);
      pa1[0] = *(const float4*)n1; pa1[1] = *(const float4*)(n1 + 4);
    }
    const char* bbase = Bs + (ks * 4 + lg) * 1040 + lr * 16;
    #pragma unroll
    for (int fn = 0; fn < 4; ++fn) {
      bf16x8 bf = *(const bf16x8*)(bbase + fn * 256);
      acc[0][fn] = __builtin_amdgcn_mfma_f32_16x16x32_bf16(af0, bf, acc[0][fn], 0, 0, 0);
      acc[1][fn] = __builtin_amdgcn_mfma_f32_16x16x32_bf16(af1, bf, acc[1][fn], 0, 0, 0);
    }
  }

  #pragma unroll
  for (int fm = 0; fm < 2; ++fm) {
    #pragma unroll
    for (int r = 0; r < 4; ++r) {
      int vrow = v0 + w * 32 + fm * 16 + lg * 4 + r;
      if (vrow < V_) {
        float bias = vb[vrow];
        #pragma unroll
        for (int fn = 0; fn < 4; ++fn) {
          int b = fn * 16 + lr;
          out[(size_t)b * V_ + vrow] = acc[fm][fn][r] + bias;
        }
      }
    }
  }
}

// K7a: per-(chunk,batch) softmax partials over V
#define VCH 6283
__global__ __launch_bounds__(256) void k_sm1(const float* __restrict__ out,
                                             float* __restrict__ pst) {
  int c = blockIdx.x, b = blockIdx.y, tid = threadIdx.x;
  __shared__ float sm[256];
  const float* row = out + (size_t)b * V_;
  int v0 = c * VCH, v1 = min(v0 + VCH, V_);
  float mx = -3.0e38f;
  for (int v = v0 + tid; v < v1; v += 256) mx = fmaxf(mx, row[v]);
  sm[tid] = mx; __syncthreads();
  for (int st = 128; st; st >>= 1) { if (tid < st) sm[tid] = fmaxf(sm[tid], sm[tid + st]); __syncthreads(); }
  mx = sm[0]; __syncthreads();
  float sum = 0.f;
  for (int v = v0 + tid; v < v1; v += 256) sum += __expf(row[v] - mx);
  sm[tid] = sum; __syncthreads();
  for (int st = 128; st; st >>= 1) { if (tid < st) sm[tid] += sm[tid + st]; __syncthreads(); }
  if (!tid) { pst[(b * 8 + c) * 2] = mx; pst[(b * 8 + c) * 2 + 1] = sm[0]; }
}

// K7b: merge chunk partials
__global__ __launch_bounds__(64) void k_sm2(const float* __restrict__ pst,
                                            float* __restrict__ stats) {
  int b = threadIdx.x;
  float mx = -3.0e38f;
  #pragma unroll
  for (int c = 0; c < 8; ++c) mx = fmaxf(mx, pst[(b * 8 + c) * 2]);
  float s = 0.f;
  #pragma unroll
  for (int c = 0; c < 8; ++c)
    s += pst[(b * 8 + c) * 2 + 1] * __expf(pst[(b * 8 + c) * 2] - mx);
  stats[b * 2] = mx; stats[b * 2 + 1] = s;
}

// K8: out = p_gen * softmax(logits) in place
__global__ __launch_bounds__(256) void k_final(float* __restrict__ out,
                                               const float* __restrict__ stats,
                                               const float* __restrict__ pg) {
  int v = blockIdx.x * 256 + threadIdx.x;
  int b = blockIdx.y;
  if (v < V_) {
    float mx = stats[b * 2];
    float scale = pg[b] / stats[b * 2 + 1];
    size_t i = (size_t)b * V_ + v;
    out[i] = scale * __expf(out[i] - mx);
  }
}

// K9: scatter attention into vocab
__global__ __launch_bounds__(256) void k_scatter(float* __restrict__ out,
                                                 const float* __restrict__ attn,
                                                 const int* __restrict__ einp,
                                                 const float* __restrict__ pg) {
  int b = blockIdx.y;
  int s = blockIdx.x * 256 + threadIdx.x;
  int v = einp[b * 2048 + s];
  float w = (1.f - pg[b]) * attn[b * 2048 + s];
  atomicAdd(out + (size_t)b * V_ + v, w);
}

// ---------------------------------------------------------------------------
extern "C" void kernel_launch(void* const* d_in, const int* in_sizes, int n_in,
                              void* d_out, int out_size, void* d_ws, size_t ws_size,
                              hipStream_t stream) {
  const float* enc  = (const float*)d_in[0];
  const float* h0   = (const float*)d_in[1];
  const float* c0   = (const float*)d_in[2];
  const int*   dec  = (const int*)d_in[3];
  const int*   einp = (const int*)d_in[4];
  const float* et   = (const float*)d_in[5];
  const float* whw  = (const float*)d_in[6];
  const float* whb  = (const float*)d_in[7];
  const float* wsw  = (const float*)d_in[8];
  const float* wsbv = (const float*)d_in[9];
  const float* av   = (const float*)d_in[10];
  const float* wih  = (const float*)d_in[11];
  const float* whh  = (const float*)d_in[12];
  const float* bih  = (const float*)d_in[13];
  const float* bhh  = (const float*)d_in[14];
  const float* whv  = (const float*)d_in[15];
  const float* wsv  = (const float*)d_in[16];
  const float* wxv  = (const float*)d_in[17];
  const float* vw   = (const float*)d_in[18];
  const float* vb   = (const float*)d_in[19];
  float* out = (float*)d_out;

  char* ws = (char*)d_ws;
  unsigned short* Wb = (unsigned short*)(ws + 0);        // 1,048,576
  float* wsbt  = (float*)(ws + 1048576);                 //   131,072
  float* e     = (float*)(ws + 1179648);                 //   524,288
  float* attn  = (float*)(ws + 1703936);                 //   524,288
  float* cpgp  = (float*)(ws + 2228224);                 // 8,388,608 (cp, then gp)
  float* xb    = (float*)(ws + 10616832);                //   458,752
  float* cw    = (float*)(ws + 11075584);                //       256
  float* pg    = (float*)(ws + 11075840);                //       256
  float* stats = (float*)(ws + 11076096);                //       512
  float* pst   = (float*)(ws + 11076608);                //     4,096

  k_convw  <<<2048, 256, 0, stream>>>(whw, Wb);
  k_wsapp  <<<128, 256, 0, stream>>>(h0, wsw, wsbv, whb, wsbt);
  k_energy <<<1024, 256, 0, stream>>>(enc, Wb, wsbt, av, e);
  k_attnsm <<<64, 256, 0, stream>>>(e, attn);
  k_ctx    <<<dim3(32, 64), 256, 0, stream>>>(enc, attn, cpgp);
  k_xprep  <<<64, 256, 0, stream>>>(cpgp, et, dec, h0, whv, wxv, xb, cw);
  k_gates  <<<dim3(32, 4), 256, 0, stream>>>(wih, whh, xb, cpgp);
  k_lstm   <<<64, 512, 0, stream>>>(cpgp, bih, bhh, c0, cw, wsv, out, pg);
  k_logits <<<393, 256, 0, stream>>>(vw, vb, out + (size_t)B_ * V_, out);
  k_sm1    <<<dim3(8, 64), 256, 0, stream>>>(out, pst);
  k_sm2    <<<1, 64, 0, stream>>>(pst, stats);
  k_final  <<<dim3(197, 64), 256, 0, stream>>>(out, stats, pg);
  k_scatter<<<dim3(8, 64), 256, 0, stream>>>(out, attn, einp, pg);
}

// Round 9
// 701.702 us; speedup vs baseline: 2.6654x; 2.5471x over previous
//
#include <hip/hip_runtime.h>

// Problem constants
#define B_   64
#define S_   2048
#define E_   1024
#define H_   512
#define EMB_ 256
#define V_   50257
#define M_   (B_*S_)

typedef __attribute__((ext_vector_type(8))) short bf16x8;   // 8 bf16 = 4 VGPR
typedef __attribute__((ext_vector_type(4))) float f32x4;

__device__ __forceinline__ unsigned short f2bf(float f) {
  unsigned int u = __float_as_uint(f);
  u += 0x7fffu + ((u >> 16) & 1u);          // round-to-nearest-even
  return (unsigned short)(u >> 16);
}
__device__ __forceinline__ unsigned pk2(float a, float b) {
  return (unsigned)f2bf(a) | ((unsigned)f2bf(b) << 16);
}
__device__ __forceinline__ float sigm(float x)  { return 1.f / (1.f + __expf(-x)); }
__device__ __forceinline__ float tanh_f(float x){ return 1.f - 2.f / (1.f + __expf(2.f * x)); }

// ---------------------------------------------------------------------------
// K1a: attn_wh_w (512x1024 f32) -> bf16, PRE-SWIZZLED Bs image per K-tile:
// Wb byte [kt*65536 + n*128 + (kb ^ ((n&7)<<4))] = bf16 of whw[n][kt*64 + kb/2]
__global__ __launch_bounds__(256) void k_convw(const float* __restrict__ w,
                                               unsigned short* __restrict__ wb) {
  int i = blockIdx.x * 256 + threadIdx.x;     // 524288 ushorts
  int kt = i >> 15;
  int rem = (i << 1) & 65535;                 // byte offset within kt image
  int n = rem >> 7;
  int sb = rem & 127;
  int kb = sb ^ ((n & 7) << 4);
  int k = kt * 64 + (kb >> 1);
  wb[i] = f2bf(w[((size_t)n << 10) + k]);
}

// K1b: wsb_tot[b][n] = attn_wh_b[n] + attn_ws_b[n] + h0[b]·attn_ws_w[n]
__global__ __launch_bounds__(256) void k_wsapp(const float* __restrict__ h0,
                                               const float* __restrict__ wsw,
                                               const float* __restrict__ wsb,
                                               const float* __restrict__ whb,
                                               float* __restrict__ outw) {
  int g = blockIdx.x * 256 + threadIdx.x;
  int b = g >> 9, n = g & 511;
  const float* hr = h0 + b * 512;
  const float* wr = wsw + (size_t)n * 512;
  float acc = 0.f;
  for (int k = 0; k < 512; k += 4) {
    float4 a = *(const float4*)(hr + k);
    float4 w = *(const float4*)(wr + k);
    acc += a.x*w.x + a.y*w.y + a.z*w.z + a.w*w.w;
  }
  outw[g] = acc + wsb[n] + whb[n];
}

// ---------------------------------------------------------------------------
// K2 v7: fused energy GEMM. 512 thr / 8 waves (2m x 4n), wave tile 64x128,
// block tile 128m x 512n, K-step 64. acc[4][8]=128 regs (round-3-proven no-spill
// budget: ~124 VGPR + 128 AGPR). LDS: As 16KB single + Bs 2x64KB dbuf = 144KB,
// 1 block/CU. enc fetched exactly once. All LDS patterns are the round-8
// measured-zero-conflict family.
__global__ __launch_bounds__(512, 2) void k_energy(
    const float* __restrict__ enc, const unsigned short* __restrict__ Wb,
    const float* __restrict__ wsb, const float* __restrict__ av,
    float* __restrict__ eout)
{
  __shared__ __attribute__((aligned(16))) char lds[147456]; // As[0,16K) Bs0[16K,80K) Bs1[80K,144K)

  const int tid = threadIdx.x;
  const int w = tid >> 6, lane = tid & 63, lr = lane & 15, lg = lane >> 4;
  const int wm = w >> 2, wn = w & 3;          // wave tile 64m x 128n
  const int m0 = blockIdx.x * 128;
  const int bb = m0 >> 11;                    // batch index

  f32x4 acc[4][8];
  #pragma unroll
  for (int i = 0; i < 4; ++i)
    #pragma unroll
    for (int j = 0; j < 8; ++j)
      #pragma unroll
      for (int r = 0; r < 4; ++r) acc[i][j][r] = 0.f;

  // A staging: thread t -> row t>>2, quarter t&3 (16 floats -> 32B bf16)
  const int arow = tid >> 2, aq = tid & 3;
  const float* aptr = enc + ((size_t)(m0 + arow) << 10) + aq * 16;
  const int aswz = (arow & 7) << 4;

  float4 ar[4]; uint4 br[8];
  auto issueA = [&](int kt) {
    const float* ap = aptr + kt * 64;
    #pragma unroll
    for (int i = 0; i < 4; ++i) ar[i] = *(const float4*)(ap + i * 4);
  };
  auto issueB = [&](int kt) {
    const uint4* bp = (const uint4*)Wb + kt * 4096;
    #pragma unroll
    for (int i = 0; i < 8; ++i) br[i] = bp[i * 512 + tid];  // lane-contiguous
  };
  auto stageA = [&]() {
    uint4 pv0, pv1;
    pv0.x = pk2(ar[0].x, ar[0].y); pv0.y = pk2(ar[0].z, ar[0].w);
    pv0.z = pk2(ar[1].x, ar[1].y); pv0.w = pk2(ar[1].z, ar[1].w);
    pv1.x = pk2(ar[2].x, ar[2].y); pv1.y = pk2(ar[2].z, ar[2].w);
    pv1.z = pk2(ar[3].x, ar[3].y); pv1.w = pk2(ar[3].z, ar[3].w);
    char* ab = lds + arow * 128;
    *(uint4*)(ab + ((aq * 32 +  0) ^ aswz)) = pv0;
    *(uint4*)(ab + ((aq * 32 + 16) ^ aswz)) = pv1;
  };
  auto stageB = [&](int d) {
    uint4* bd = (uint4*)(lds + 16384 + d * 65536);
    #pragma unroll
    for (int i = 0; i < 8; ++i) bd[i * 512 + tid] = br[i];  // lane-contiguous
  };

  const int swz = (lr & 7) << 4;
  int abase[4];
  #pragma unroll
  for (int fm = 0; fm < 4; ++fm) abase[fm] = (wm * 64 + fm * 16 + lr) * 128;
  int boff[8];
  #pragma unroll
  for (int fn = 0; fn < 8; ++fn) boff[fn] = (wn * 128 + fn * 16 + lr) * 128;

  // prologue
  issueA(0); issueB(0);
  stageA(); stageB(0);
  __syncthreads();

  for (int kt = 0; kt < 16; ++kt) {
    const int buf = kt & 1;
    if (kt < 15) { issueB(kt + 1); issueA(kt + 1); }   // in flight under compute
    const char* bbuf = lds + 16384 + buf * 65536;
    #pragma unroll
    for (int ks = 0; ks < 2; ++ks) {
      const int ko = (ks * 64 + lg * 16) ^ swz;
      bf16x8 af[4];
      #pragma unroll
      for (int fm = 0; fm < 4; ++fm) af[fm] = *(const bf16x8*)(lds + abase[fm] + ko);
      #pragma unroll
      for (int fn = 0; fn < 8; ++fn) {
        bf16x8 bf = *(const bf16x8*)(bbuf + boff[fn] + ko);
        #pragma unroll
        for (int fm = 0; fm < 4; ++fm)
          acc[fm][fn] = __builtin_amdgcn_mfma_f32_16x16x32_bf16(af[fm], bf, acc[fm][fn], 0, 0, 0);
      }
    }
    if (kt < 15) {
      __syncthreads();                  // all waves done reading As
      stageA(); stageB(buf ^ 1);        // write-late into idle buffer
      __syncthreads();                  // stage visible
    }
  }

  // epilogue: e_row = sum_n av[n]*tanh(acc + wsb[b][n]); deterministic reduce
  float cw_[8], cv_[8];
  #pragma unroll
  for (int fn = 0; fn < 8; ++fn) {
    int col = wn * 128 + fn * 16 + lr;
    cw_[fn] = wsb[bb * 512 + col];
    cv_[fn] = av[col];
  }
  __syncthreads();                      // all LDS reads done; reuse As as red
  float* red = (float*)lds;             // [4 wn][128]
  #pragma unroll
  for (int fm = 0; fm < 4; ++fm) {
    #pragma unroll
    for (int r = 0; r < 4; ++r) {
      float v = 0.f;
      #pragma unroll
      for (int fn = 0; fn < 8; ++fn)
        v += cv_[fn] * tanh_f(acc[fm][fn][r] + cw_[fn]);  // C/D: col=lane&15, row=(lane>>4)*4+r
      v += __shfl_xor(v, 1); v += __shfl_xor(v, 2);
      v += __shfl_xor(v, 4); v += __shfl_xor(v, 8);
      if (lr == 0) red[wn * 128 + wm * 64 + fm * 16 + lg * 4 + r] = v;
    }
  }
  __syncthreads();
  if (tid < 128)
    eout[m0 + tid] = red[tid] + red[128 + tid] + red[256 + tid] + red[384 + tid];
}

// ---------------------------------------------------------------------------
// K3: softmax over S per batch
__global__ __launch_bounds__(256) void k_attnsm(const float* __restrict__ e,
                                                float* __restrict__ attn) {
  int b = blockIdx.x, tid = threadIdx.x;
  __shared__ float sm[256];
  float ev[8]; float mx = -3.0e38f;
  #pragma unroll
  for (int i = 0; i < 8; ++i) {
    float v = e[b * 2048 + i * 256 + tid];
    ev[i] = v; mx = fmaxf(mx, v);
  }
  sm[tid] = mx; __syncthreads();
  for (int st = 128; st; st >>= 1) { if (tid < st) sm[tid] = fmaxf(sm[tid], sm[tid + st]); __syncthreads(); }
  mx = sm[0]; __syncthreads();
  float sum = 0.f;
  #pragma unroll
  for (int i = 0; i < 8; ++i) { ev[i] = __expf(ev[i] - mx); sum += ev[i]; }
  sm[tid] = sum; __syncthreads();
  for (int st = 128; st; st >>= 1) { if (tid < st) sm[tid] += sm[tid + st]; __syncthreads(); }
  float inv = 1.f / sm[0];
  #pragma unroll
  for (int i = 0; i < 8; ++i) attn[b * 2048 + i * 256 + tid] = ev[i] * inv;
}

// K4: context partials over 32 s-chunks of 64
__global__ __launch_bounds__(256) void k_ctx(const float* __restrict__ enc,
                                             const float* __restrict__ attn,
                                             float* __restrict__ cp) {
  int sc = blockIdx.x, b = blockIdx.y, tid = threadIdx.x;
  int e0 = tid * 4;
  float ax = 0.f, ay = 0.f, az = 0.f, aw = 0.f;
  const float* base = enc + (((size_t)b * 2048 + sc * 64) << 10) + e0;
  const float* awt = attn + b * 2048 + sc * 64;
  #pragma unroll 8
  for (int s = 0; s < 64; ++s) {
    float wv = awt[s];
    float4 v = *(const float4*)(base + ((size_t)s << 10));
    ax += wv * v.x; ay += wv * v.y; az += wv * v.z; aw += wv * v.w;
  }
  float4 o; o.x = ax; o.y = ay; o.z = az; o.w = aw;
  *(float4*)(cp + ((size_t)sc * 64 + b) * 1024 + e0) = o;
}

// K5a: reduce context, build xb[b][k], cw[b] = ctx·wh_vec + embed·wx_vec
__global__ __launch_bounds__(256) void k_xprep(const float* __restrict__ cp,
                                               const float* __restrict__ et,
                                               const int* __restrict__ dec,
                                               const float* __restrict__ h0,
                                               const float* __restrict__ whv,
                                               const float* __restrict__ wxv,
                                               float* __restrict__ xb,
                                               float* __restrict__ cw) {
  int b = blockIdx.x, tid = threadIdx.x;
  __shared__ float sm[256];
  float acc = 0.f;
  for (int j = tid; j < 1024; j += 256) {
    float s = 0.f;
    #pragma unroll
    for (int sc = 0; sc < 32; ++sc) s += cp[((size_t)sc * 64 + b) * 1024 + j];
    xb[b * 1792 + j] = s;
    acc += s * whv[j];
  }
  int e = dec[b];
  {
    int j = tid;
    float s = et[(size_t)e * 256 + j];
    xb[b * 1792 + 1024 + j] = s;
    acc += s * wxv[j];
  }
  for (int j = tid; j < 512; j += 256)
    xb[b * 1792 + 1280 + j] = h0[b * 512 + j];
  sm[tid] = acc; __syncthreads();
  for (int st = 128; st; st >>= 1) { if (tid < st) sm[tid] += sm[tid + st]; __syncthreads(); }
  if (!tid) cw[b] = sm[0];
}

// K5b: gate partials via MFMA. Block = 64 j-rows x 64 b, k-slab 448.
__global__ __launch_bounds__(256, 2) void k_gates(const float* __restrict__ wih,
                                                  const float* __restrict__ whh,
                                                  const float* __restrict__ xb,
                                                  float* __restrict__ gp) {
  __shared__ __attribute__((aligned(16))) char Bs[56 * 1040];
  const int tid = threadIdx.x;
  const int w = tid >> 6, lane = tid & 63, lr = lane & 15, lg = lane >> 4;
  const int j0 = blockIdx.x * 64;
  const int sl = blockIdx.y;
  const int k0 = sl * 448;

  #pragma unroll
  for (int i = 0; i < 16; ++i) {
    int slot = i * 256 + tid;
    int kq = slot & 63, n = slot >> 6;
    if (kq < 56) {
      const float4* p = (const float4*)(xb + n * 1792 + k0 + kq * 8);
      float4 x0 = p[0], x1 = p[1];
      uint4 pv;
      pv.x = pk2(x0.x, x0.y); pv.y = pk2(x0.z, x0.w);
      pv.z = pk2(x1.x, x1.y); pv.w = pk2(x1.z, x1.w);
      *(uint4*)(Bs + kq * 1040 + n * 16) = pv;
    }
  }
  __syncthreads();

  f32x4 acc[4];
  #pragma unroll
  for (int fn = 0; fn < 4; ++fn)
    #pragma unroll
    for (int r = 0; r < 4; ++r) acc[fn][r] = 0.f;

  const int j = j0 + w * 16 + lr;
  for (int ks = 0; ks < 14; ++ks) {
    int kg = k0 + ks * 32 + lg * 8;
    const float* ap = (kg < 1280) ? (wih + (size_t)j * 1280 + kg)
                                  : (whh + (size_t)j * 512 + (kg - 1280));
    float4 x0 = *(const float4*)ap, x1 = *(const float4*)(ap + 4);
    bf16x8 af;
    unsigned* au = (unsigned*)&af;
    au[0] = pk2(x0.x, x0.y); au[1] = pk2(x0.z, x0.w);
    au[2] = pk2(x1.x, x1.y); au[3] = pk2(x1.z, x1.w);
    #pragma unroll
    for (int fn = 0; fn < 4; ++fn) {
      bf16x8 bf = *(const bf16x8*)(Bs + (ks * 4 + lg) * 1040 + (fn * 16 + lr) * 16);
      acc[fn] = __builtin_amdgcn_mfma_f32_16x16x32_bf16(af, bf, acc[fn], 0, 0, 0);
    }
  }
  #pragma unroll
  for (int fn = 0; fn < 4; ++fn) {
    int b = fn * 16 + lr;
    #pragma unroll
    for (int r = 0; r < 4; ++r) {
      int jr = j0 + w * 16 + lg * 4 + r;
      gp[((size_t)sl * 64 + b) * 2048 + jr] = acc[fn][r];
    }
  }
}

// K5c: LSTM cell + h_t,c_t outputs + p_gen (reduce 4 k-slabs)
__global__ __launch_bounds__(512) void k_lstm(const float* __restrict__ gp,
                                              const float* __restrict__ bih,
                                              const float* __restrict__ bhh,
                                              const float* __restrict__ c0,
                                              const float* __restrict__ cw,
                                              const float* __restrict__ wsv,
                                              float* __restrict__ dout,
                                              float* __restrict__ pg) {
  int b = blockIdx.x, h = threadIdx.x;
  __shared__ float sm[512];
  float gi = bih[h]        + bhh[h];
  float gf = bih[512 + h]  + bhh[512 + h];
  float gg = bih[1024 + h] + bhh[1024 + h];
  float go = bih[1536 + h] + bhh[1536 + h];
  #pragma unroll
  for (int kc = 0; kc < 4; ++kc) {
    const float* g = gp + ((size_t)kc * 64 + b) * 2048;
    gi += g[h]; gf += g[512 + h]; gg += g[1024 + h]; go += g[1536 + h];
  }
  float c  = sigm(gf) * c0[b * 512 + h] + sigm(gi) * tanh_f(gg);
  float ht = sigm(go) * tanh_f(c);
  dout[(size_t)B_ * V_ + b * 512 + h] = ht;
  dout[(size_t)B_ * V_ + B_ * H_ + b * 512 + h] = c;
  sm[h] = ht * wsv[h];
  __syncthreads();
  for (int st = 256; st; st >>= 1) { if (h < st) sm[h] += sm[h + st]; __syncthreads(); }
  if (!h) pg[b] = sigm(cw[b] + sm[0]);
}

// K6: vocab logits via MFMA. Block = 128 v-rows x all 64 batches.
__global__ __launch_bounds__(256, 2) void k_logits(const float* __restrict__ vw,
                                                   const float* __restrict__ vb,
                                                   const float* __restrict__ ht,
                                                   float* __restrict__ out) {
  __shared__ __attribute__((aligned(16))) char Bs[64 * 1040];
  const int tid = threadIdx.x;
  const int w = tid >> 6, lane = tid & 63, lr = lane & 15, lg = lane >> 4;
  const int v0 = blockIdx.x * 128;

  #pragma unroll
  for (int i = 0; i < 16; ++i) {
    int slot = i * 256 + tid;
    int kq = slot & 63, n = slot >> 6;
    const float4* p = (const float4*)(ht + n * 512 + kq * 8);
    float4 x0 = p[0], x1 = p[1];
    uint4 pv;
    pv.x = pk2(x0.x, x0.y); pv.y = pk2(x0.z, x0.w);
    pv.z = pk2(x1.x, x1.y); pv.w = pk2(x1.z, x1.w);
    *(uint4*)(Bs + kq * 1040 + n * 16) = pv;
  }
  __syncthreads();

  f32x4 acc[2][4];
  #pragma unroll
  for (int fm = 0; fm < 2; ++fm)
    #pragma unroll
    for (int fn = 0; fn < 4; ++fn)
      #pragma unroll
      for (int r = 0; r < 4; ++r) acc[fm][fn][r] = 0.f;

  int row0 = v0 + w * 32 + lr;
  int row1 = row0 + 16;
  const float* a0p = vw + (size_t)min(row0, V_ - 1) * 512 + lg * 8;
  const float* a1p = vw + (size_t)min(row1, V_ - 1) * 512 + lg * 8;

  float4 pa0[2], pa1[2];
  pa0[0] = *(const float4*)a0p; pa0[1] = *(const float4*)(a0p + 4);
  pa1[0] = *(const float4*)a1p; pa1[1] = *(const float4*)(a1p + 4);

  for (int ks = 0; ks < 16; ++ks) {
    bf16x8 af0, af1;
    {
      unsigned* u = (unsigned*)&af0;
      u[0] = pk2(pa0[0].x, pa0[0].y); u[1] = pk2(pa0[0].z, pa0[0].w);
      u[2] = pk2(pa0[1].x, pa0[1].y); u[3] = pk2(pa0[1].z, pa0[1].w);
      unsigned* v = (unsigned*)&af1;
      v[0] = pk2(pa1[0].x, pa1[0].y); v[1] = pk2(pa1[0].z, pa1[0].w);
      v[2] = pk2(pa1[1].x, pa1[1].y); v[3] = pk2(pa1[1].z, pa1[1].w);
    }
    if (ks < 15) {
      const float* n0 = a0p + (ks + 1) * 32;
      const float* n1 = a1p + (ks + 1) * 32;
      pa0[0] = *(const float4*)n0; pa0[1] = *(const float4*)(n0 + 4);
      pa1[0] = *(const float4*)n1; pa1[1] = *(const float4*)(n1 + 4);
    }
    const char* bbase = Bs + (ks * 4 + lg) * 1040 + lr * 16;
    #pragma unroll
    for (int fn = 0; fn < 4; ++fn) {
      bf16x8 bf = *(const bf16x8*)(bbase + fn * 256);
      acc[0][fn] = __builtin_amdgcn_mfma_f32_16x16x32_bf16(af0, bf, acc[0][fn], 0, 0, 0);
      acc[1][fn] = __builtin_amdgcn_mfma_f32_16x16x32_bf16(af1, bf, acc[1][fn], 0, 0, 0);
    }
  }

  #pragma unroll
  for (int fm = 0; fm < 2; ++fm) {
    #pragma unroll
    for (int r = 0; r < 4; ++r) {
      int vrow = v0 + w * 32 + fm * 16 + lg * 4 + r;
      if (vrow < V_) {
        float bias = vb[vrow];
        #pragma unroll
        for (int fn = 0; fn < 4; ++fn) {
          int b = fn * 16 + lr;
          out[(size_t)b * V_ + vrow] = acc[fm][fn][r] + bias;
        }
      }
    }
  }
}

// K7a: per-(chunk,batch) softmax partials over V
#define VCH 6283
__global__ __launch_bounds__(256) void k_sm1(const float* __restrict__ out,
                                             float* __restrict__ pst) {
  int c = blockIdx.x, b = blockIdx.y, tid = threadIdx.x;
  __shared__ float sm[256];
  const float* row = out + (size_t)b * V_;
  int v0 = c * VCH, v1 = min(v0 + VCH, V_);
  float mx = -3.0e38f;
  for (int v = v0 + tid; v < v1; v += 256) mx = fmaxf(mx, row[v]);
  sm[tid] = mx; __syncthreads();
  for (int st = 128; st; st >>= 1) { if (tid < st) sm[tid] = fmaxf(sm[tid], sm[tid + st]); __syncthreads(); }
  mx = sm[0]; __syncthreads();
  float sum = 0.f;
  for (int v = v0 + tid; v < v1; v += 256) sum += __expf(row[v] - mx);
  sm[tid] = sum; __syncthreads();
  for (int st = 128; st; st >>= 1) { if (tid < st) sm[tid] += sm[tid + st]; __syncthreads(); }
  if (!tid) { pst[(b * 8 + c) * 2] = mx; pst[(b * 8 + c) * 2 + 1] = sm[0]; }
}

// K7b: merge chunk partials
__global__ __launch_bounds__(64) void k_sm2(const float* __restrict__ pst,
                                            float* __restrict__ stats) {
  int b = threadIdx.x;
  float mx = -3.0e38f;
  #pragma unroll
  for (int c = 0; c < 8; ++c) mx = fmaxf(mx, pst[(b * 8 + c) * 2]);
  float s = 0.f;
  #pragma unroll
  for (int c = 0; c < 8; ++c)
    s += pst[(b * 8 + c) * 2 + 1] * __expf(pst[(b * 8 + c) * 2] - mx);
  stats[b * 2] = mx; stats[b * 2 + 1] = s;
}

// K8: out = p_gen * softmax(logits) in place
__global__ __launch_bounds__(256) void k_final(float* __restrict__ out,
                                               const float* __restrict__ stats,
                                               const float* __restrict__ pg) {
  int v = blockIdx.x * 256 + threadIdx.x;
  int b = blockIdx.y;
  if (v < V_) {
    float mx = stats[b * 2];
    float scale = pg[b] / stats[b * 2 + 1];
    size_t i = (size_t)b * V_ + v;
    out[i] = scale * __expf(out[i] - mx);
  }
}

// K9: scatter attention into vocab
__global__ __launch_bounds__(256) void k_scatter(float* __restrict__ out,
                                                 const float* __restrict__ attn,
                                                 const int* __restrict__ einp,
                                                 const float* __restrict__ pg) {
  int b = blockIdx.y;
  int s = blockIdx.x * 256 + threadIdx.x;
  int v = einp[b * 2048 + s];
  float w = (1.f - pg[b]) * attn[b * 2048 + s];
  atomicAdd(out + (size_t)b * V_ + v, w);
}

// ---------------------------------------------------------------------------
extern "C" void kernel_launch(void* const* d_in, const int* in_sizes, int n_in,
                              void* d_out, int out_size, void* d_ws, size_t ws_size,
                              hipStream_t stream) {
  const float* enc  = (const float*)d_in[0];
  const float* h0   = (const float*)d_in[1];
  const float* c0   = (const float*)d_in[2];
  const int*   dec  = (const int*)d_in[3];
  const int*   einp = (const int*)d_in[4];
  const float* et   = (const float*)d_in[5];
  const float* whw  = (const float*)d_in[6];
  const float* whb  = (const float*)d_in[7];
  const float* wsw  = (const float*)d_in[8];
  const float* wsbv = (const float*)d_in[9];
  const float* av   = (const float*)d_in[10];
  const float* wih  = (const float*)d_in[11];
  const float* whh  = (const float*)d_in[12];
  const float* bih  = (const float*)d_in[13];
  const float* bhh  = (const float*)d_in[14];
  const float* whv  = (const float*)d_in[15];
  const float* wsv  = (const float*)d_in[16];
  const float* wxv  = (const float*)d_in[17];
  const float* vw   = (const float*)d_in[18];
  const float* vb   = (const float*)d_in[19];
  float* out = (float*)d_out;

  char* ws = (char*)d_ws;
  unsigned short* Wb = (unsigned short*)(ws + 0);        // 1,048,576
  float* wsbt  = (float*)(ws + 1048576);                 //   131,072
  float* e     = (float*)(ws + 1179648);                 //   524,288
  float* attn  = (float*)(ws + 1703936);                 //   524,288
  float* cpgp  = (float*)(ws + 2228224);                 // 8,388,608 (cp, then gp)
  float* xb    = (float*)(ws + 10616832);                //   458,752
  float* cw    = (float*)(ws + 11075584);                //       256
  float* pg    = (float*)(ws + 11075840);                //       256
  float* stats = (float*)(ws + 11076096);                //       512
  float* pst   = (float*)(ws + 11076608);                //     4,096

  k_convw  <<<2048, 256, 0, stream>>>(whw, Wb);
  k_wsapp  <<<128, 256, 0, stream>>>(h0, wsw, wsbv, whb, wsbt);
  k_energy <<<1024, 512, 0, stream>>>(enc, Wb, wsbt, av, e);
  k_attnsm <<<64, 256, 0, stream>>>(e, attn);
  k_ctx    <<<dim3(32, 64), 256, 0, stream>>>(enc, attn, cpgp);
  k_xprep  <<<64, 256, 0, stream>>>(cpgp, et, dec, h0, whv, wxv, xb, cw);
  k_gates  <<<dim3(32, 4), 256, 0, stream>>>(wih, whh, xb, cpgp);
  k_lstm   <<<64, 512, 0, stream>>>(cpgp, bih, bhh, c0, cw, wsv, out, pg);
  k_logits <<<393, 256, 0, stream>>>(vw, vb, out + (size_t)B_ * V_, out);
  k_sm1    <<<dim3(8, 64), 256, 0, stream>>>(out, pst);
  k_sm2    <<<1, 64, 0, stream>>>(pst, stats);
  k_final  <<<dim3(197, 64), 256, 0, stream>>>(out, stats, pg);
  k_scatter<<<dim3(8, 64), 256, 0, stream>>>(out, attn, einp, pg);
}

// Round 10
// 426.981 us; speedup vs baseline: 4.3804x; 1.6434x over previous
//
#include <hip/hip_runtime.h>

// Problem constants
#define B_   64
#define S_   2048
#define E_   1024
#define H_   512
#define EMB_ 256
#define V_   50257
#define M_   (B_*S_)

typedef __attribute__((ext_vector_type(8))) short bf16x8;   // 8 bf16 = 4 VGPR
typedef __attribute__((ext_vector_type(4))) float f32x4;

__device__ __forceinline__ unsigned short f2bf(float f) {
  unsigned int u = __float_as_uint(f);
  u += 0x7fffu + ((u >> 16) & 1u);          // round-to-nearest-even
  return (unsigned short)(u >> 16);
}
__device__ __forceinline__ unsigned pk2(float a, float b) {
  return (unsigned)f2bf(a) | ((unsigned)f2bf(b) << 16);
}
__device__ __forceinline__ float sigm(float x)  { return 1.f / (1.f + __expf(-x)); }
__device__ __forceinline__ float tanh_f(float x){ return 1.f - 2.f / (1.f + __expf(2.f * x)); }

// ---------------------------------------------------------------------------
// K1a: attn_wh_w (512x1024 f32) -> bf16, PRE-SWIZZLED Bs image per K-tile:
// Wb byte [kt*65536 + n*128 + (kb ^ ((n&7)<<4))] = bf16 of whw[n][kt*64 + kb/2]
__global__ __launch_bounds__(256) void k_convw(const float* __restrict__ w,
                                               unsigned short* __restrict__ wb) {
  int i = blockIdx.x * 256 + threadIdx.x;     // 524288 ushorts
  int kt = i >> 15;
  int rem = (i << 1) & 65535;                 // byte offset within kt image
  int n = rem >> 7;
  int sb = rem & 127;
  int kb = sb ^ ((n & 7) << 4);
  int k = kt * 64 + (kb >> 1);
  wb[i] = f2bf(w[((size_t)n << 10) + k]);
}

// K1b: wsb_tot[b][n] = attn_wh_b[n] + attn_ws_b[n] + h0[b]·attn_ws_w[n]
__global__ __launch_bounds__(256) void k_wsapp(const float* __restrict__ h0,
                                               const float* __restrict__ wsw,
                                               const float* __restrict__ wsb,
                                               const float* __restrict__ whb,
                                               float* __restrict__ outw) {
  int g = blockIdx.x * 256 + threadIdx.x;
  int b = g >> 9, n = g & 511;
  const float* hr = h0 + b * 512;
  const float* wr = wsw + (size_t)n * 512;
  float acc = 0.f;
  for (int k = 0; k < 512; k += 4) {
    float4 a = *(const float4*)(hr + k);
    float4 w = *(const float4*)(wr + k);
    acc += a.x*w.x + a.y*w.y + a.z*w.z + a.w*w.w;
  }
  outw[g] = acc + wsb[n] + whb[n];
}

// ---------------------------------------------------------------------------
// K2 v8: fused energy GEMM. 512 thr / 8 waves (2m x 4n), wave tile 64x128,
// block tile 128m x 512n, K-step 64. A reg-staged (fp32->bf16), B staged via
// global_load_lds (pre-swizzled image -> linear LDS copy, no VGPR round-trip).
// Full double-buffer: As 2x16KB + Bs 2x64KB = 160KB LDS, ONE barrier per kt.
// Live regs ~ 128 acc + ~80 arch << cap: no spill (round-9 WRITE_SIZE=719MB fix).
__global__ __launch_bounds__(512) void k_energy(
    const float* __restrict__ enc, const unsigned short* __restrict__ Wb,
    const float* __restrict__ wsb, const float* __restrict__ av,
    float* __restrict__ eout)
{
  __shared__ __attribute__((aligned(16))) char lds[163840];
  // As0 [0,16K)  As1 [16K,32K)  Bs0 [32K,96K)  Bs1 [96K,160K)

  const int tid = threadIdx.x;
  const int w = tid >> 6, lane = tid & 63, lr = lane & 15, lg = lane >> 4;
  const int wm = w >> 2, wn = w & 3;          // wave tile 64m x 128n
  const int m0 = blockIdx.x * 128;
  const int bb = m0 >> 11;                    // batch index

  f32x4 acc[4][8];
  #pragma unroll
  for (int i = 0; i < 4; ++i)
    #pragma unroll
    for (int j = 0; j < 8; ++j)
      #pragma unroll
      for (int r = 0; r < 4; ++r) acc[i][j][r] = 0.f;

  // A staging: thread t -> row t>>2, quarter t&3 (16 floats -> 32B bf16)
  const int arow = tid >> 2, aq = tid & 3;
  const float* aptr = enc + ((size_t)(m0 + arow) << 10) + aq * 16;
  const int aswz = (arow & 7) << 4;

  float4 ar[4];
  auto issueA = [&](int kt) {
    const float* ap = aptr + kt * 64;
    #pragma unroll
    for (int i = 0; i < 4; ++i) ar[i] = *(const float4*)(ap + i * 4);
  };
  auto stageA = [&](int d) {
    uint4 pv0, pv1;
    pv0.x = pk2(ar[0].x, ar[0].y); pv0.y = pk2(ar[0].z, ar[0].w);
    pv0.z = pk2(ar[1].x, ar[1].y); pv0.w = pk2(ar[1].z, ar[1].w);
    pv1.x = pk2(ar[2].x, ar[2].y); pv1.y = pk2(ar[2].z, ar[2].w);
    pv1.z = pk2(ar[3].x, ar[3].y); pv1.w = pk2(ar[3].z, ar[3].w);
    char* ab = lds + d * 16384 + arow * 128;
    *(uint4*)(ab + ((aq * 32 +  0) ^ aswz)) = pv0;
    *(uint4*)(ab + ((aq * 32 + 16) ^ aswz)) = pv1;
  };
  // B staging: direct global->LDS, 8 x 1KB per wave, lane-linear (16B/lane)
  auto gllB = [&](int kt, int d) {
    const char* g = (const char*)Wb + kt * 65536 + w * 8192 + lane * 16;
    char* l = lds + 32768 + d * 65536 + w * 8192 + lane * 16;
    #pragma unroll
    for (int i = 0; i < 8; ++i)
      __builtin_amdgcn_global_load_lds(
          (const __attribute__((address_space(1))) unsigned int*)(g + i * 1024),
          (__attribute__((address_space(3))) unsigned int*)(l + i * 1024),
          16, 0, 0);
  };

  const int swz = (lr & 7) << 4;
  int abase[4];
  #pragma unroll
  for (int fm = 0; fm < 4; ++fm) abase[fm] = (wm * 64 + fm * 16 + lr) * 128;
  int boff[8];
  #pragma unroll
  for (int fn = 0; fn < 8; ++fn) boff[fn] = 32768 + (wn * 128 + fn * 16 + lr) * 128;

  // prologue
  issueA(0);
  gllB(0, 0);
  stageA(0);
  __syncthreads();                      // drains vmcnt+lgkm: As0/Bs0 ready

  for (int kt = 0; kt < 16; ++kt) {
    const int buf = kt & 1;
    if (kt < 15) {
      issueA(kt + 1);                   // A loads in flight under compute
      gllB(kt + 1, buf ^ 1);            // B lands directly in idle buffer
    }
    const int abuf = buf * 16384;
    const int bbuf = buf * 65536;
    #pragma unroll
    for (int ks = 0; ks < 2; ++ks) {
      const int ko = (ks * 64 + lg * 16) ^ swz;
      bf16x8 af[4];
      #pragma unroll
      for (int fm = 0; fm < 4; ++fm) af[fm] = *(const bf16x8*)(lds + abuf + abase[fm] + ko);
      #pragma unroll
      for (int fn = 0; fn < 8; ++fn) {
        bf16x8 bf = *(const bf16x8*)(lds + bbuf + boff[fn] + ko);
        #pragma unroll
        for (int fm = 0; fm < 4; ++fm)
          acc[fm][fn] = __builtin_amdgcn_mfma_f32_16x16x32_bf16(af[fm], bf, acc[fm][fn], 0, 0, 0);
      }
    }
    if (kt < 15) stageA(buf ^ 1);       // convert+write into idle A buffer
    __syncthreads();                    // gll landed + ds_writes visible + reads done
  }

  // epilogue: e_row = sum_n av[n]*tanh(acc + wsb[b][n]); deterministic reduce
  float cw_[8], cv_[8];
  #pragma unroll
  for (int fn = 0; fn < 8; ++fn) {
    int col = wn * 128 + fn * 16 + lr;
    cw_[fn] = wsb[bb * 512 + col];
    cv_[fn] = av[col];
  }
  float* red = (float*)lds;             // reuse As area: [4 wn][128]
  #pragma unroll
  for (int fm = 0; fm < 4; ++fm) {
    #pragma unroll
    for (int r = 0; r < 4; ++r) {
      float v = 0.f;
      #pragma unroll
      for (int fn = 0; fn < 8; ++fn)
        v += cv_[fn] * tanh_f(acc[fm][fn][r] + cw_[fn]);  // C/D: col=lane&15, row=(lane>>4)*4+r
      v += __shfl_xor(v, 1); v += __shfl_xor(v, 2);
      v += __shfl_xor(v, 4); v += __shfl_xor(v, 8);
      if (lr == 0) red[wn * 128 + wm * 64 + fm * 16 + lg * 4 + r] = v;
    }
  }
  __syncthreads();
  if (tid < 128)
    eout[m0 + tid] = red[tid] + red[128 + tid] + red[256 + tid] + red[384 + tid];
}

// ---------------------------------------------------------------------------
// K3: softmax over S per batch
__global__ __launch_bounds__(256) void k_attnsm(const float* __restrict__ e,
                                                float* __restrict__ attn) {
  int b = blockIdx.x, tid = threadIdx.x;
  __shared__ float sm[256];
  float ev[8]; float mx = -3.0e38f;
  #pragma unroll
  for (int i = 0; i < 8; ++i) {
    float v = e[b * 2048 + i * 256 + tid];
    ev[i] = v; mx = fmaxf(mx, v);
  }
  sm[tid] = mx; __syncthreads();
  for (int st = 128; st; st >>= 1) { if (tid < st) sm[tid] = fmaxf(sm[tid], sm[tid + st]); __syncthreads(); }
  mx = sm[0]; __syncthreads();
  float sum = 0.f;
  #pragma unroll
  for (int i = 0; i < 8; ++i) { ev[i] = __expf(ev[i] - mx); sum += ev[i]; }
  sm[tid] = sum; __syncthreads();
  for (int st = 128; st; st >>= 1) { if (tid < st) sm[tid] += sm[tid + st]; __syncthreads(); }
  float inv = 1.f / sm[0];
  #pragma unroll
  for (int i = 0; i < 8; ++i) attn[b * 2048 + i * 256 + tid] = ev[i] * inv;
}

// K4: context partials over 32 s-chunks of 64
__global__ __launch_bounds__(256) void k_ctx(const float* __restrict__ enc,
                                             const float* __restrict__ attn,
                                             float* __restrict__ cp) {
  int sc = blockIdx.x, b = blockIdx.y, tid = threadIdx.x;
  int e0 = tid * 4;
  float ax = 0.f, ay = 0.f, az = 0.f, aw = 0.f;
  const float* base = enc + (((size_t)b * 2048 + sc * 64) << 10) + e0;
  const float* awt = attn + b * 2048 + sc * 64;
  #pragma unroll 8
  for (int s = 0; s < 64; ++s) {
    float wv = awt[s];
    float4 v = *(const float4*)(base + ((size_t)s << 10));
    ax += wv * v.x; ay += wv * v.y; az += wv * v.z; aw += wv * v.w;
  }
  float4 o; o.x = ax; o.y = ay; o.z = az; o.w = aw;
  *(float4*)(cp + ((size_t)sc * 64 + b) * 1024 + e0) = o;
}

// K5a: reduce context, build xb[b][k], cw[b] = ctx·wh_vec + embed·wx_vec
__global__ __launch_bounds__(256) void k_xprep(const float* __restrict__ cp,
                                               const float* __restrict__ et,
                                               const int* __restrict__ dec,
                                               const float* __restrict__ h0,
                                               const float* __restrict__ whv,
                                               const float* __restrict__ wxv,
                                               float* __restrict__ xb,
                                               float* __restrict__ cw) {
  int b = blockIdx.x, tid = threadIdx.x;
  __shared__ float sm[256];
  float acc = 0.f;
  for (int j = tid; j < 1024; j += 256) {
    float s = 0.f;
    #pragma unroll
    for (int sc = 0; sc < 32; ++sc) s += cp[((size_t)sc * 64 + b) * 1024 + j];
    xb[b * 1792 + j] = s;
    acc += s * whv[j];
  }
  int e = dec[b];
  {
    int j = tid;
    float s = et[(size_t)e * 256 + j];
    xb[b * 1792 + 1024 + j] = s;
    acc += s * wxv[j];
  }
  for (int j = tid; j < 512; j += 256)
    xb[b * 1792 + 1280 + j] = h0[b * 512 + j];
  sm[tid] = acc; __syncthreads();
  for (int st = 128; st; st >>= 1) { if (tid < st) sm[tid] += sm[tid + st]; __syncthreads(); }
  if (!tid) cw[b] = sm[0];
}

// K5b: gate partials via MFMA. Block = 64 j-rows x 64 b, k-slab 448.
__global__ __launch_bounds__(256, 2) void k_gates(const float* __restrict__ wih,
                                                  const float* __restrict__ whh,
                                                  const float* __restrict__ xb,
                                                  float* __restrict__ gp) {
  __shared__ __attribute__((aligned(16))) char Bs[56 * 1040];
  const int tid = threadIdx.x;
  const int w = tid >> 6, lane = tid & 63, lr = lane & 15, lg = lane >> 4;
  const int j0 = blockIdx.x * 64;
  const int sl = blockIdx.y;
  const int k0 = sl * 448;

  #pragma unroll
  for (int i = 0; i < 16; ++i) {
    int slot = i * 256 + tid;
    int kq = slot & 63, n = slot >> 6;
    if (kq < 56) {
      const float4* p = (const float4*)(xb + n * 1792 + k0 + kq * 8);
      float4 x0 = p[0], x1 = p[1];
      uint4 pv;
      pv.x = pk2(x0.x, x0.y); pv.y = pk2(x0.z, x0.w);
      pv.z = pk2(x1.x, x1.y); pv.w = pk2(x1.z, x1.w);
      *(uint4*)(Bs + kq * 1040 + n * 16) = pv;
    }
  }
  __syncthreads();

  f32x4 acc[4];
  #pragma unroll
  for (int fn = 0; fn < 4; ++fn)
    #pragma unroll
    for (int r = 0; r < 4; ++r) acc[fn][r] = 0.f;

  const int j = j0 + w * 16 + lr;
  for (int ks = 0; ks < 14; ++ks) {
    int kg = k0 + ks * 32 + lg * 8;
    const float* ap = (kg < 1280) ? (wih + (size_t)j * 1280 + kg)
                                  : (whh + (size_t)j * 512 + (kg - 1280));
    float4 x0 = *(const float4*)ap, x1 = *(const float4*)(ap + 4);
    bf16x8 af;
    unsigned* au = (unsigned*)&af;
    au[0] = pk2(x0.x, x0.y); au[1] = pk2(x0.z, x0.w);
    au[2] = pk2(x1.x, x1.y); au[3] = pk2(x1.z, x1.w);
    #pragma unroll
    for (int fn = 0; fn < 4; ++fn) {
      bf16x8 bf = *(const bf16x8*)(Bs + (ks * 4 + lg) * 1040 + (fn * 16 + lr) * 16);
      acc[fn] = __builtin_amdgcn_mfma_f32_16x16x32_bf16(af, bf, acc[fn], 0, 0, 0);
    }
  }
  #pragma unroll
  for (int fn = 0; fn < 4; ++fn) {
    int b = fn * 16 + lr;
    #pragma unroll
    for (int r = 0; r < 4; ++r) {
      int jr = j0 + w * 16 + lg * 4 + r;
      gp[((size_t)sl * 64 + b) * 2048 + jr] = acc[fn][r];
    }
  }
}

// K5c: LSTM cell + h_t,c_t outputs + p_gen (reduce 4 k-slabs)
__global__ __launch_bounds__(512) void k_lstm(const float* __restrict__ gp,
                                              const float* __restrict__ bih,
                                              const float* __restrict__ bhh,
                                              const float* __restrict__ c0,
                                              const float* __restrict__ cw,
                                              const float* __restrict__ wsv,
                                              float* __restrict__ dout,
                                              float* __restrict__ pg) {
  int b = blockIdx.x, h = threadIdx.x;
  __shared__ float sm[512];
  float gi = bih[h]        + bhh[h];
  float gf = bih[512 + h]  + bhh[512 + h];
  float gg = bih[1024 + h] + bhh[1024 + h];
  float go = bih[1536 + h] + bhh[1536 + h];
  #pragma unroll
  for (int kc = 0; kc < 4; ++kc) {
    const float* g = gp + ((size_t)kc * 64 + b) * 2048;
    gi += g[h]; gf += g[512 + h]; gg += g[1024 + h]; go += g[1536 + h];
  }
  float c  = sigm(gf) * c0[b * 512 + h] + sigm(gi) * tanh_f(gg);
  float ht = sigm(go) * tanh_f(c);
  dout[(size_t)B_ * V_ + b * 512 + h] = ht;
  dout[(size_t)B_ * V_ + B_ * H_ + b * 512 + h] = c;
  sm[h] = ht * wsv[h];
  __syncthreads();
  for (int st = 256; st; st >>= 1) { if (h < st) sm[h] += sm[h + st]; __syncthreads(); }
  if (!h) pg[b] = sigm(cw[b] + sm[0]);
}

// K6: vocab logits via MFMA. Block = 128 v-rows x all 64 batches.
__global__ __launch_bounds__(256, 2) void k_logits(const float* __restrict__ vw,
                                                   const float* __restrict__ vb,
                                                   const float* __restrict__ ht,
                                                   float* __restrict__ out) {
  __shared__ __attribute__((aligned(16))) char Bs[64 * 1040];
  const int tid = threadIdx.x;
  const int w = tid >> 6, lane = tid & 63, lr = lane & 15, lg = lane >> 4;
  const int v0 = blockIdx.x * 128;

  #pragma unroll
  for (int i = 0; i < 16; ++i) {
    int slot = i * 256 + tid;
    int kq = slot & 63, n = slot >> 6;
    const float4* p = (const float4*)(ht + n * 512 + kq * 8);
    float4 x0 = p[0], x1 = p[1];
    uint4 pv;
    pv.x = pk2(x0.x, x0.y); pv.y = pk2(x0.z, x0.w);
    pv.z = pk2(x1.x, x1.y); pv.w = pk2(x1.z, x1.w);
    *(uint4*)(Bs + kq * 1040 + n * 16) = pv;
  }
  __syncthreads();

  f32x4 acc[2][4];
  #pragma unroll
  for (int fm = 0; fm < 2; ++fm)
    #pragma unroll
    for (int fn = 0; fn < 4; ++fn)
      #pragma unroll
      for (int r = 0; r < 4; ++r) acc[fm][fn][r] = 0.f;

  int row0 = v0 + w * 32 + lr;
  int row1 = row0 + 16;
  const float* a0p = vw + (size_t)min(row0, V_ - 1) * 512 + lg * 8;
  const float* a1p = vw + (size_t)min(row1, V_ - 1) * 512 + lg * 8;

  float4 pa0[2], pa1[2];
  pa0[0] = *(const float4*)a0p; pa0[1] = *(const float4*)(a0p + 4);
  pa1[0] = *(const float4*)a1p; pa1[1] = *(const float4*)(a1p + 4);

  for (int ks = 0; ks < 16; ++ks) {
    bf16x8 af0, af1;
    {
      unsigned* u = (unsigned*)&af0;
      u[0] = pk2(pa0[0].x, pa0[0].y); u[1] = pk2(pa0[0].z, pa0[0].w);
      u[2] = pk2(pa0[1].x, pa0[1].y); u[3] = pk2(pa0[1].z, pa0[1].w);
      unsigned* v = (unsigned*)&af1;
      v[0] = pk2(pa1[0].x, pa1[0].y); v[1] = pk2(pa1[0].z, pa1[0].w);
      v[2] = pk2(pa1[1].x, pa1[1].y); v[3] = pk2(pa1[1].z, pa1[1].w);
    }
    if (ks < 15) {
      const float* n0 = a0p + (ks + 1) * 32;
      const float* n1 = a1p + (ks + 1) * 32;
      pa0[0] = *(const float4*)n0; pa0[1] = *(const float4*)(n0 + 4);
      pa1[0] = *(const float4*)n1; pa1[1] = *(const float4*)(n1 + 4);
    }
    const char* bbase = Bs + (ks * 4 + lg) * 1040 + lr * 16;
    #pragma unroll
    for (int fn = 0; fn < 4; ++fn) {
      bf16x8 bf = *(const bf16x8*)(bbase + fn * 256);
      acc[0][fn] = __builtin_amdgcn_mfma_f32_16x16x32_bf16(af0, bf, acc[0][fn], 0, 0, 0);
      acc[1][fn] = __builtin_amdgcn_mfma_f32_16x16x32_bf16(af1, bf, acc[1][fn], 0, 0, 0);
    }
  }

  #pragma unroll
  for (int fm = 0; fm < 2; ++fm) {
    #pragma unroll
    for (int r = 0; r < 4; ++r) {
      int vrow = v0 + w * 32 + fm * 16 + lg * 4 + r;
      if (vrow < V_) {
        float bias = vb[vrow];
        #pragma unroll
        for (int fn = 0; fn < 4; ++fn) {
          int b = fn * 16 + lr;
          out[(size_t)b * V_ + vrow] = acc[fm][fn][r] + bias;
        }
      }
    }
  }
}

// K7a: per-(chunk,batch) softmax partials over V
#define VCH 6283
__global__ __launch_bounds__(256) void k_sm1(const float* __restrict__ out,
                                             float* __restrict__ pst) {
  int c = blockIdx.x, b = blockIdx.y, tid = threadIdx.x;
  __shared__ float sm[256];
  const float* row = out + (size_t)b * V_;
  int v0 = c * VCH, v1 = min(v0 + VCH, V_);
  float mx = -3.0e38f;
  for (int v = v0 + tid; v < v1; v += 256) mx = fmaxf(mx, row[v]);
  sm[tid] = mx; __syncthreads();
  for (int st = 128; st; st >>= 1) { if (tid < st) sm[tid] = fmaxf(sm[tid], sm[tid + st]); __syncthreads(); }
  mx = sm[0]; __syncthreads();
  float sum = 0.f;
  for (int v = v0 + tid; v < v1; v += 256) sum += __expf(row[v] - mx);
  sm[tid] = sum; __syncthreads();
  for (int st = 128; st; st >>= 1) { if (tid < st) sm[tid] += sm[tid + st]; __syncthreads(); }
  if (!tid) { pst[(b * 8 + c) * 2] = mx; pst[(b * 8 + c) * 2 + 1] = sm[0]; }
}

// K7b: merge chunk partials
__global__ __launch_bounds__(64) void k_sm2(const float* __restrict__ pst,
                                            float* __restrict__ stats) {
  int b = threadIdx.x;
  float mx = -3.0e38f;
  #pragma unroll
  for (int c = 0; c < 8; ++c) mx = fmaxf(mx, pst[(b * 8 + c) * 2]);
  float s = 0.f;
  #pragma unroll
  for (int c = 0; c < 8; ++c)
    s += pst[(b * 8 + c) * 2 + 1] * __expf(pst[(b * 8 + c) * 2] - mx);
  stats[b * 2] = mx; stats[b * 2 + 1] = s;
}

// K8: out = p_gen * softmax(logits) in place
__global__ __launch_bounds__(256) void k_final(float* __restrict__ out,
                                               const float* __restrict__ stats,
                                               const float* __restrict__ pg) {
  int v = blockIdx.x * 256 + threadIdx.x;
  int b = blockIdx.y;
  if (v < V_) {
    float mx = stats[b * 2];
    float scale = pg[b] / stats[b * 2 + 1];
    size_t i = (size_t)b * V_ + v;
    out[i] = scale * __expf(out[i] - mx);
  }
}

// K9: scatter attention into vocab
__global__ __launch_bounds__(256) void k_scatter(float* __restrict__ out,
                                                 const float* __restrict__ attn,
                                                 const int* __restrict__ einp,
                                                 const float* __restrict__ pg) {
  int b = blockIdx.y;
  int s = blockIdx.x * 256 + threadIdx.x;
  int v = einp[b * 2048 + s];
  float w = (1.f - pg[b]) * attn[b * 2048 + s];
  atomicAdd(out + (size_t)b * V_ + v, w);
}

// ---------------------------------------------------------------------------
extern "C" void kernel_launch(void* const* d_in, const int* in_sizes, int n_in,
                              void* d_out, int out_size, void* d_ws, size_t ws_size,
                              hipStream_t stream) {
  const float* enc  = (const float*)d_in[0];
  const float* h0   = (const float*)d_in[1];
  const float* c0   = (const float*)d_in[2];
  const int*   dec  = (const int*)d_in[3];
  const int*   einp = (const int*)d_in[4];
  const float* et   = (const float*)d_in[5];
  const float* whw  = (const float*)d_in[6];
  const float* whb  = (const float*)d_in[7];
  const float* wsw  = (const float*)d_in[8];
  const float* wsbv = (const float*)d_in[9];
  const float* av   = (const float*)d_in[10];
  const float* wih  = (const float*)d_in[11];
  const float* whh  = (const float*)d_in[12];
  const float* bih  = (const float*)d_in[13];
  const float* bhh  = (const float*)d_in[14];
  const float* whv  = (const float*)d_in[15];
  const float* wsv  = (const float*)d_in[16];
  const float* wxv  = (const float*)d_in[17];
  const float* vw   = (const float*)d_in[18];
  const float* vb   = (const float*)d_in[19];
  float* out = (float*)d_out;

  char* ws = (char*)d_ws;
  unsigned short* Wb = (unsigned short*)(ws + 0);        // 1,048,576
  float* wsbt  = (float*)(ws + 1048576);                 //   131,072
  float* e     = (float*)(ws + 1179648);                 //   524,288
  float* attn  = (float*)(ws + 1703936);                 //   524,288
  float* cpgp  = (float*)(ws + 2228224);                 // 8,388,608 (cp, then gp)
  float* xb    = (float*)(ws + 10616832);                //   458,752
  float* cw    = (float*)(ws + 11075584);                //       256
  float* pg    = (float*)(ws + 11075840);                //       256
  float* stats = (float*)(ws + 11076096);                //       512
  float* pst   = (float*)(ws + 11076608);                //     4,096

  k_convw  <<<2048, 256, 0, stream>>>(whw, Wb);
  k_wsapp  <<<128, 256, 0, stream>>>(h0, wsw, wsbv, whb, wsbt);
  k_energy <<<1024, 512, 0, stream>>>(enc, Wb, wsbt, av, e);
  k_attnsm <<<64, 256, 0, stream>>>(e, attn);
  k_ctx    <<<dim3(32, 64), 256, 0, stream>>>(enc, attn, cpgp);
  k_xprep  <<<64, 256, 0, stream>>>(cpgp, et, dec, h0, whv, wxv, xb, cw);
  k_gates  <<<dim3(32, 4), 256, 0, stream>>>(wih, whh, xb, cpgp);
  k_lstm   <<<64, 512, 0, stream>>>(cpgp, bih, bhh, c0, cw, wsv, out, pg);
  k_logits <<<393, 256, 0, stream>>>(vw, vb, out + (size_t)B_ * V_, out);
  k_sm1    <<<dim3(8, 64), 256, 0, stream>>>(out, pst);
  k_sm2    <<<1, 64, 0, stream>>>(pst, stats);
  k_final  <<<dim3(197, 64), 256, 0, stream>>>(out, stats, pg);
  k_scatter<<<dim3(8, 64), 256, 0, stream>>>(out, attn, einp, pg);
}